// Round 7
// baseline (315.126 us; speedup 1.0000x reference)
//
#include <hip/hip_runtime.h>

// LatentMixer on MI355X. bf16-MFMA pipeline with runtime input-dtype sniffing.
// B=8, C=512, HW=4096, L=16, heads=8, d=64, scale=0.125, eps=1e-12.
// R2: out = (w_proj@blockdiag(V)) @ P + bias (algebraic fusion).
// R3: attn1 fused into kv-GEMM epilogue; 128x128 tiles.
// R4: global_load_lds width=16 staging.  R5: XOR-swizzled glld layout.
// R7: native __bf16 cast f2bf.
// R8: dbuf prefetch gemm (kvattn1 90->66us).  R9: setprio(1) around dbuf compute.
// R10: attn2p2 on dbuf gemm (281.7us best).
// R11: launch-count 11->6: k_mega1 = {xt + weight-prep + bias + ql(raw reads) + gnum-zero},
//      k_kvlnm = {kvl + klnorm + mmat} (kvl/gvl round-trips removed).

typedef __bf16 bf16x8 __attribute__((ext_vector_type(8)));
typedef float floatx4 __attribute__((ext_vector_type(4)));
typedef short short8_t __attribute__((ext_vector_type(8)));
typedef short short4_t __attribute__((ext_vector_type(4)));

#define DEV __device__ __forceinline__

DEV float bf2f(unsigned short u){ union{unsigned int i; float f;} v; v.i = ((unsigned int)u)<<16; return v.f; }
DEV unsigned short f2bf(float f){
  __bf16 h = (__bf16)f;                  // RTNE; compiler packs pairs into v_cvt_pk_bf16_f32
  unsigned short u; __builtin_memcpy(&u, &h, 2); return u;
}

// async global->LDS, 16 B per lane; LDS dest = base + lane*16 (wave-uniform base!)
DEV void glds16(const void* g, void* l){
  __builtin_amdgcn_global_load_lds((const __attribute__((address_space(1))) void*)g,
                                   (__attribute__((address_space(3))) void*)l, 16, 0, 0);
}

// ---------------- workspace layout (bytes) ----------------
#define OFF_XT     256ull                          // xT bf16 [8][4096][512]
#define OFF_KVX    (OFF_XT + 33554432ull)          // region reused: Pg bf16 [8][4096][128] + Mg
#define OFF_WKVX   (OFF_KVX + 67108864ull)         // w_kv_x bf16   (weights contiguous from here)
#define OFF_WQX    (OFF_WKVX + 1048576ull)         // w_q_x bf16
#define OFF_WKVL   (OFF_WQX + 524288ull)           // w_kv_lat bf16
#define OFF_WPROJ  (OFF_WKVL + 1048576ull)         // w_proj bf16
#define OFF_WQLAT  (OFF_WPROJ + 524288ull)         // w_q_lat bf16
#define OFF_LATF   (OFF_WQLAT + 524288ull)         // (unused since R11)
#define OFF_BIAS   (OFF_LATF + 32768ull)           // bias f32 [512]
#define OFF_QLH    (OFF_BIAS + 4096ull)            // ql-hat f32 [h][l][64] (0.125 folded)
#define OFF_GNUM   (OFF_QLH + 32768ull)            // attn1 numerator f32 [b][h][l][64]
#define OFF_GDEN   (OFF_GNUM + 524288ull)          // attn1 denominator f32 [b][h][l] (contig after gnum)
#define OFF_KVL    (OFF_GDEN + 4096ull)            // (unused since R11)
#define OFF_KHAT   (OFF_KVL + 524288ull)           // k-hat f32 [b][h][l][64] (0.125 folded)
#define OFF_GVL    (OFF_KHAT + 524288ull)          // (unused since R11)

// ---------------- dtype sniff ----------------
__global__ void k_sniff(const unsigned short* __restrict__ x, int* flag){
  int t = threadIdx.x;
  int m = 0;
  for (int i = t; i < 4096; i += 256){ int e = (x[i]>>7)&0xFF; m = (e>m)?e:m; }
  __shared__ int red[256];
  red[t] = m; __syncthreads();
  for (int s = 128; s > 0; s >>= 1){ if (t < s) red[t] = (red[t+s]>red[t])?red[t+s]:red[t]; __syncthreads(); }
  if (t == 0) flag[0] = (red[0] > 150) ? 1 : 0;   // 1 => fp32 inputs, 0 => bf16 inputs
}

// ---------------- mega1: xt (4096) | weight prep (896) | bias (1) | ql (8) | zero (129) ----------------
__global__ __launch_bounds__(256) void k_mega1(const void* __restrict__ xraw,
                                               const void* __restrict__ slat,
                                               const void* __restrict__ swqlat,
                                               const void* s0, const void* s1, const void* s2,
                                               const void* s3, const void* s4,
                                               const void* __restrict__ sbias,
                                               unsigned short* __restrict__ xT,
                                               unsigned short* __restrict__ wdst,
                                               float* __restrict__ biasf,
                                               float* __restrict__ qlh,
                                               float* __restrict__ zro,
                                               const int* __restrict__ flag){
  extern __shared__ char smr[];
  int bid = blockIdx.x, t = threadIdx.x;
  int isf = *flag;
  if (bid < 4096){
    // ---- transpose x[b][c][n] -> xT[b][n][c], XOR-swizzled LDS tile ----
    unsigned short (*tile)[72] = (unsigned short(*)[72])smr;   // [64][72]
    int nb = bid&63, cb = (bid>>6)&7, b = bid>>9;
    int n0 = nb*64, c0 = cb*64;
    if (isf){
      const float* xp = (const float*)xraw;
#pragma unroll
      for (int i = 0; i < 4; ++i){
        int ch = i*256 + t; int c = ch>>4, n4 = (ch&15)*4;
        float4 v = *(const float4*)&xp[((size_t)(b*512 + c0 + c))*4096 + n0 + n4];
        int cc = n4 ^ (((c>>3)&7)<<3);
        tile[c][cc+0]=f2bf(v.x); tile[c][cc+1]=f2bf(v.y); tile[c][cc+2]=f2bf(v.z); tile[c][cc+3]=f2bf(v.w);
      }
    } else {
      const unsigned short* xp = (const unsigned short*)xraw;
#pragma unroll
      for (int i = 0; i < 2; ++i){
        int ch = i*256 + t; int c = ch>>3, n8 = (ch&7)*8;
        *(short8_t*)&tile[c][n8 ^ (((c>>3)&7)<<3)] =
          *(const short8_t*)&xp[((size_t)(b*512 + c0 + c))*4096 + n0 + n8];
      }
    }
    __syncthreads();
#pragma unroll
    for (int i = 0; i < 2; ++i){
      int ch = i*256 + t; int n = ch>>3, c8 = (ch&7)*8;
      unsigned short tmp[8] __attribute__((aligned(16)));
#pragma unroll
      for (int j = 0; j < 8; ++j){
        int c = c8 + j;
        tmp[j] = tile[c][n ^ (((c>>3)&7)<<3)];
      }
      *(short8_t*)&xT[((size_t)(b*4096 + n0 + n))*512 + c0 + c8] = *(short8_t*)tmp;
    }
  } else if (bid < 4992){
    // ---- weight convert into contiguous wdst ----
    int e = (bid-4096)*2048 + t*8;
    const void* src; int off;
    if (e < 524288)      { src = s0; off = e; }
    else if (e < 786432) { src = s1; off = e - 524288; }
    else if (e < 1310720){ src = s2; off = e - 786432; }
    else if (e < 1572864){ src = s3; off = e - 1310720; }
    else                 { src = s4; off = e - 1572864; }
    if (isf){
      const float* s = (const float*)src + off;
      float4 v0 = *(const float4*)(s);
      float4 v1 = *(const float4*)(s+4);
      unsigned short tmp[8] __attribute__((aligned(16)));
      tmp[0]=f2bf(v0.x); tmp[1]=f2bf(v0.y); tmp[2]=f2bf(v0.z); tmp[3]=f2bf(v0.w);
      tmp[4]=f2bf(v1.x); tmp[5]=f2bf(v1.y); tmp[6]=f2bf(v1.z); tmp[7]=f2bf(v1.w);
      *(short8_t*)&wdst[e] = *(short8_t*)tmp;
    } else {
      *(short8_t*)&wdst[e] = *(const short8_t*)((const unsigned short*)src + off);
    }
  } else if (bid == 4992){
    // ---- bias (all 512) ----
    biasf[t]       = isf ? ((const float*)sbias)[t]       : bf2f(((const unsigned short*)sbias)[t]);
    biasf[t + 256] = isf ? ((const float*)sbias)[t + 256] : bf2f(((const unsigned short*)sbias)[t + 256]);
  } else if (bid < 5001){
    // ---- ql = w_q_lat @ latents + normalize (raw-input reads; independent of prep blocks) ----
    int h = bid - 4993, o0 = h*64;
    float* latb = (float*)smr;                           // [128][16] = 8192
    unsigned short* wt = (unsigned short*)(smr + 8192);  // [64][136] = 17408
    float* qbuf = (float*)(smr + 25600);                 // [64][16] = 4096
    float* rinv = (float*)(smr + 29696);                 // [16]
    int o = t>>2, l4 = (t&3)*4;
    float acc[4] = {0.f,0.f,0.f,0.f};
    for (int kk = 0; kk < 512; kk += 128){
      __syncthreads();
#pragma unroll
      for (int j = 0; j < 8; ++j){
        int i = j*256 + t;
        latb[i] = isf ? ((const float*)slat)[kk*16 + i] : bf2f(((const unsigned short*)slat)[kk*16 + i]);
      }
#pragma unroll
      for (int j = 0; j < 4; ++j){
        int ch = j*256 + t; int r = ch>>4, kc = (ch&15)*8;
        if (isf){
          const float* s = (const float*)swqlat + (size_t)(o0+r)*512 + kk + kc;
          float4 v0 = *(const float4*)(s);
          float4 v1 = *(const float4*)(s+4);
          unsigned short tmp[8] __attribute__((aligned(16)));
          tmp[0]=f2bf(v0.x); tmp[1]=f2bf(v0.y); tmp[2]=f2bf(v0.z); tmp[3]=f2bf(v0.w);
          tmp[4]=f2bf(v1.x); tmp[5]=f2bf(v1.y); tmp[6]=f2bf(v1.z); tmp[7]=f2bf(v1.w);
          *(short8_t*)&wt[r*136 + kc] = *(short8_t*)tmp;
        } else {
          *(short8_t*)&wt[r*136 + kc] =
            *(const short8_t*)((const unsigned short*)swqlat + (size_t)(o0+r)*512 + kk + kc);
        }
      }
      __syncthreads();
      for (int k = 0; k < 128; ++k){
        float w = bf2f(wt[o*136 + k]);
        const float* lr = &latb[k*16 + l4];
#pragma unroll
        for (int j = 0; j < 4; ++j) acc[j] += w*lr[j];
      }
    }
#pragma unroll
    for (int j = 0; j < 4; ++j) qbuf[o*16 + l4 + j] = acc[j];
    __syncthreads();
    if (t < 16){
      float ss = 0.f;
      for (int oo = 0; oo < 64; ++oo){ float v = qbuf[oo*16 + t]; ss += v*v; }
      rinv[t] = 0.125f / fmaxf(sqrtf(ss), 1e-12f);
    }
    __syncthreads();
#pragma unroll
    for (int j = 0; j < 4; ++j) qlh[(h*16 + l4 + j)*64 + o] = acc[j]*rinv[l4 + j];
  } else {
    // ---- zero gnum+gden (528384 B = 33024 float4, 129 blocks x 256 thr exactly) ----
    int i = (bid-5001)*256 + t;
    float4 z; z.x=0.f; z.y=0.f; z.z=0.f; z.w=0.f;
    ((float4*)zro)[i] = z;
  }
}

// ---------------- shared staging helper (XOR-swizzled k8 within row) ----------------
DEV void stage_ab(const unsigned short* __restrict__ Ap0, const unsigned short* __restrict__ Ap1,
                  const unsigned short* __restrict__ Bp, int kk,
                  unsigned short* At, unsigned short* Bt, int wave, int rsub, int koff){
#pragma unroll
  for (int c2 = 0; c2 < 4; ++c2){
    int chunk = wave*4 + c2;           // 0..15, wave-uniform
    int row = chunk*8 + rsub;
    const unsigned short* gp = (chunk < 8) ? (Ap0 + (size_t)row*512 + kk + koff)
                                           : (Ap1 + (size_t)(row-64)*512 + kk + koff);
    glds16(gp, At + chunk*512);
  }
#pragma unroll
  for (int c2 = 0; c2 < 4; ++c2){
    int chunk = wave*4 + c2;
    int row = chunk*8 + rsub;
    glds16(Bp + (size_t)row*512 + kk + koff, Bt + chunk*512);
  }
}

// ---------------- 128x128 GEMM, double-buffered prefetch (64KB staging) ----------------
DEV void gemm128_db(const unsigned short* __restrict__ Ap0, const unsigned short* __restrict__ Ap1,
                    const unsigned short* __restrict__ Bp,
                    char* smr, floatx4 (&acc)[4][4]){
  unsigned short* At0 = (unsigned short*)smr;
  unsigned short* Bt0 = (unsigned short*)(smr + 16384);
  unsigned short* At1 = (unsigned short*)(smr + 32768);
  unsigned short* Bt1 = (unsigned short*)(smr + 49152);
  int t = threadIdx.x, lane = t&63, wave = t>>6;
  int wm = wave>>1, wn = wave&1, lr = lane&15, lq = lane>>4;
  int rsub = lane>>3;                 // 0..7: row within 8-row chunk
  int koff = ((lane&7) ^ rsub)*8;     // swizzled global k8 slot (shorts)
  int sw = lr&7;                      // read-side XOR factor
  stage_ab(Ap0, Ap1, Bp, 0, At0, Bt0, wave, rsub, koff);
  __syncthreads();                    // drains vmcnt(0): tile 0 resident
  for (int kk = 0; kk < 512; kk += 64){
    int cur = (kk>>6)&1;
    unsigned short* Ac = cur ? At1 : At0;
    unsigned short* Bc = cur ? Bt1 : Bt0;
    if (kk < 448){                    // issue next tile's loads FIRST (overlap with compute)
      stage_ab(Ap0, Ap1, Bp, kk+64, cur ? At0 : At1, cur ? Bt0 : Bt1, wave, rsub, koff);
    }
    __builtin_amdgcn_s_setprio(1);
#pragma unroll
    for (int ks = 0; ks < 2; ++ks){
      int vo = ((ks*4 + lq) ^ sw)*8;
      bf16x8 a[4], b[4];
#pragma unroll
      for (int mt = 0; mt < 4; ++mt) a[mt] = *(const bf16x8*)&Ac[(wm*64 + mt*16 + lr)*64 + vo];
#pragma unroll
      for (int nt = 0; nt < 4; ++nt) b[nt] = *(const bf16x8*)&Bc[(wn*64 + nt*16 + lr)*64 + vo];
#pragma unroll
      for (int mt = 0; mt < 4; ++mt)
#pragma unroll
        for (int nt = 0; nt < 4; ++nt)
          acc[mt][nt] = __builtin_amdgcn_mfma_f32_16x16x32_bf16(a[mt], b[nt], acc[mt][nt], 0, 0, 0);
    }
    __builtin_amdgcn_s_setprio(0);
    __syncthreads();                  // next tile's writes complete + all reads of cur done
  }
}

// ---------------- fused kv-GEMM + attn1: M-tile = [k_h(64); v_h(64)], N=128 positions ----------------
// LDS: staging dbuf 0..65536. Epilogue aliases staging: kt [128][72] @0 (18432),
// vt [64][136] @18432 (->35840), pt [16][136] @35840 (->40192).
// Above staging: qls [16][72] @65536 (->67840), ssq @67840 (->68352), wred @68352 (->68608).
__global__ __launch_bounds__(256) void k_kvattn1(const unsigned short* __restrict__ wkvx,
                                                 const unsigned short* __restrict__ xT,
                                                 const float* __restrict__ qlh2,
                                                 float* __restrict__ gnum, float* __restrict__ gden){
  int nb = blockIdx.x, h = blockIdx.y, b = blockIdx.z;
  int n0 = nb*128;
  extern __shared__ char smr[];
  unsigned short* kt  = (unsigned short*)smr;            // [128 n][72] k-hat, d contiguous
  unsigned short* vt  = (unsigned short*)(smr + 18432);  // [64 d][136]
  unsigned short* pt  = (unsigned short*)(smr + 35840);  // [16 l][136] p bf16
  unsigned short* qls = (unsigned short*)(smr + 65536);  // [16 l][72] 0.125*q-hat
  float* ssq  = (float*)(smr + 67840);                   // [128] rinv
  float* wred = (float*)(smr + 68352);                   // [4][16]
  int t = threadIdx.x, lane = t&63, wave = t>>6;
  int wm = wave>>1, wn = wave&1, lr = lane&15, lq = lane>>4;
  // stage 0.125*q-hat [16][72] (outside staging region; before GEMM to overlap)
  for (int i = t; i < 1024; i += 256) qls[(i>>6)*72 + (i&63)] = f2bf(qlh2[(size_t)h*1024 + i]);
  floatx4 acc[4][4];
  floatx4 zero = {0.f,0.f,0.f,0.f};
#pragma unroll
  for (int i = 0; i < 4; ++i) for (int j = 0; j < 4; ++j) acc[i][j] = zero;
  gemm128_db(wkvx + (size_t)(h*64)*512, wkvx + (size_t)(512 + h*64)*512,
             xT + ((size_t)(b*4096 + n0))*512, smr, acc);
  if (wm == 0){
    // k column inverse norms from f32 accumulators
#pragma unroll
    for (int nt = 0; nt < 4; ++nt){
      float s = 0.f;
#pragma unroll
      for (int mt = 0; mt < 4; ++mt)
#pragma unroll
        for (int r = 0; r < 4; ++r) s += acc[mt][nt][r]*acc[mt][nt][r];
      s += __shfl_xor(s, 16); s += __shfl_xor(s, 32);
      if (lq == 0) ssq[wn*64 + nt*16 + lr] = 1.f / fmaxf(sqrtf(s), 1e-12f);
    }
  } else {
    // v tile to LDS [d][n]
#pragma unroll
    for (int mt = 0; mt < 4; ++mt)
#pragma unroll
      for (int nt = 0; nt < 4; ++nt){
        int col = wn*64 + nt*16 + lr;
#pragma unroll
        for (int r = 0; r < 4; ++r) vt[(mt*16 + lq*4 + r)*136 + col] = f2bf(acc[mt][nt][r]);
      }
  }
  __syncthreads();
  if (wm == 0){
    // k-hat tile to LDS transposed [n][d], norm folded
#pragma unroll
    for (int nt = 0; nt < 4; ++nt){
      int col = wn*64 + nt*16 + lr;
      float rinv = ssq[col];
#pragma unroll
      for (int mt = 0; mt < 4; ++mt){
        unsigned short tmp[4] __attribute__((aligned(8)));
#pragma unroll
        for (int r = 0; r < 4; ++r) tmp[r] = f2bf(acc[mt][nt][r]*rinv);
        *(short4_t*)&kt[col*72 + mt*16 + lq*4] = *(short4_t*)tmp;
      }
    }
  }
  __syncthreads();
  // S^T[n][l] via MFMA: A = kt rows n, B = qls rows l, K=64
  floatx4 sl[2]; sl[0] = zero; sl[1] = zero;
#pragma unroll
  for (int ks = 0; ks < 2; ++ks){
    bf16x8 bb = *(const bf16x8*)&qls[lr*72 + ks*32 + lq*8];
#pragma unroll
    for (int i = 0; i < 2; ++i){
      bf16x8 aa = *(const bf16x8*)&kt[((wave*2 + i)*16 + lr)*72 + ks*32 + lq*8];
      sl[i] = __builtin_amdgcn_mfma_f32_16x16x32_bf16(aa, bb, sl[i], 0, 0, 0);
    }
  }
  // p = exp(s) (|s| <= 0.125); den partials; p to LDS [l][n]
  float dp = 0.f;
  float pv[2][4];
#pragma unroll
  for (int i = 0; i < 2; ++i)
#pragma unroll
    for (int r = 0; r < 4; ++r){ float p = __expf(sl[i][r]); pv[i][r] = p; dp += p; }
  dp += __shfl_xor(dp, 16); dp += __shfl_xor(dp, 32);
  if (lq == 0) wred[wave*16 + lr] = dp;
#pragma unroll
  for (int i = 0; i < 2; ++i){
    unsigned short tmp[4] __attribute__((aligned(8)));
#pragma unroll
    for (int r = 0; r < 4; ++r) tmp[r] = f2bf(pv[i][r]);
    *(short4_t*)&pt[lr*136 + (wave*2 + i)*16 + lq*4] = *(short4_t*)tmp;
  }
  __syncthreads();
  int bh = b*8 + h;
  if (t < 16) atomicAdd(&gden[bh*16 + t], wred[t] + wred[16+t] + wred[32+t] + wred[48+t]);
  // num^T[d][l] via MFMA: A = vt rows d (wave*16 block), B = pt rows l, K=128
  floatx4 nacc = zero;
#pragma unroll
  for (int ks = 0; ks < 4; ++ks){
    bf16x8 aa = *(const bf16x8*)&vt[(wave*16 + lr)*136 + ks*32 + lq*8];
    bf16x8 bb = *(const bf16x8*)&pt[lr*136 + ks*32 + lq*8];
    nacc = __builtin_amdgcn_mfma_f32_16x16x32_bf16(aa, bb, nacc, 0, 0, 0);
  }
  float* gp = &gnum[((size_t)bh*16 + lr)*64 + wave*16 + lq*4];
#pragma unroll
  for (int r = 0; r < 4; ++r) atomicAdd(&gp[r], nacc[r]);
}

// ---------------- kvlnm: kvl (head h rows) + kl-norm + mmat, fused. grid (h=8, b=8) ----------------
// LDS: latb [512][16] f32 @0 (32768), wt [128][136] bf16 @32768 (->67584),
// kbuf [16][68] f32 @67584 (->71936), vbuf [16][68] f32 @71936 (->76288), rl [16] @76288 (->76352).
__global__ __launch_bounds__(256) void k_kvlnm(const unsigned short* __restrict__ wkvl,
                                               const unsigned short* __restrict__ wproj,
                                               const float* __restrict__ gnum,
                                               const float* __restrict__ gden,
                                               float* __restrict__ khat,
                                               unsigned short* __restrict__ Mg){
  int h = blockIdx.x, b = blockIdx.y;
  extern __shared__ char smr[];
  float* latb = (float*)smr;                            // [512][16]
  unsigned short* wt = (unsigned short*)(smr + 32768);  // [128][136]
  float* kbuf = (float*)(smr + 67584);                  // [16 l][68] (d minor)
  float* vbuf = (float*)(smr + 71936);                  // [16 l][68]
  float* rl   = (float*)(smr + 76288);                  // [16]
  int t = threadIdx.x;
  int bh = b*8 + h;
  // latb = attn1 output (num/den) for ALL heads of this b: latb[c*16+l]
  for (int i = t; i < 8192; i += 256){
    int c = i>>4, l = i&15;
    int hs = c>>6, d = c&63;
    latb[i] = gnum[((size_t)((b*8+hs)*16 + l))*64 + d] / gden[(b*8+hs)*16 + l];
  }
  int rq = t>>4, l = t&15;        // thread covers rows rq, rq+16, ..., rq+112 at column l
  float acc[8];
#pragma unroll
  for (int j = 0; j < 8; ++j) acc[j] = 0.f;
  for (int kk = 0; kk < 512; kk += 128){
    __syncthreads();
    // stage wkvl rows for head h: r<64 -> k-rows (h*64+r), r>=64 -> v-rows (512+h*64+r-64)
#pragma unroll
    for (int j = 0; j < 8; ++j){
      int ch = j*256 + t; int r = ch>>4, kc = (ch&15)*8;
      int og = (r < 64) ? (h*64 + r) : (512 + h*64 + (r-64));
      *(short8_t*)&wt[r*136 + kc] = *(const short8_t*)&wkvl[(size_t)og*512 + kk + kc];
    }
    __syncthreads();
    for (int k = 0; k < 128; ++k){
      float lv = latb[(kk + k)*16 + l];
#pragma unroll
      for (int j = 0; j < 8; ++j) acc[j] += bf2f(wt[(j*16 + rq)*136 + k]) * lv;
    }
  }
  // scatter to kbuf/vbuf
  __syncthreads();
#pragma unroll
  for (int j = 0; j < 8; ++j){
    int row = j*16 + rq;
    if (row < 64) kbuf[l*68 + row] = acc[j];
    else          vbuf[l*68 + (row-64)] = acc[j];
  }
  __syncthreads();
  if (t < 16){
    float ss = 0.f;
    for (int d = 0; d < 64; ++d){ float v = kbuf[t*68 + d]; ss += v*v; }
    rl[t] = 0.125f / fmaxf(sqrtf(ss), 1e-12f);
  }
  __syncthreads();
  // khat [bh][l][d]
#pragma unroll
  for (int j = 0; j < 4; ++j){
    int i = j*256 + t; int ll = i>>6, d = i&63;
    khat[((size_t)bh*16 + ll)*64 + d] = kbuf[ll*68 + d]*rl[ll];
  }
  // ---- mmat: Mg[b][c][h*16+l] = sum_d wproj[c][h*64+d]*vl[l][d] ----
  float v[64];
  {
    const float* vp = &vbuf[l*68];
#pragma unroll
    for (int j = 0; j < 16; ++j){ float4 f = *(const float4*)&vp[j*4];
      v[j*4+0]=f.x; v[j*4+1]=f.y; v[j*4+2]=f.z; v[j*4+3]=f.w; }
  }
  int cq = t>>4;
  for (int cb = 0; cb < 4; ++cb){
    __syncthreads();
    // stage wproj chunk [128 c][68] (reuses wt region)
#pragma unroll
    for (int j = 0; j < 4; ++j){
      int ch = j*256 + t; int c = ch>>3, d8 = (ch&7)*8;
      *(short8_t*)&wt[c*68 + d8] = *(const short8_t*)&wproj[(size_t)(cb*128 + c)*512 + h*64 + d8];
    }
    __syncthreads();
#pragma unroll
    for (int c8 = 0; c8 < 8; ++c8){
      int c = cq*8 + c8;
      float dot = 0.f;
#pragma unroll
      for (int d = 0; d < 64; ++d) dot += bf2f(wt[c*68 + d]) * v[d];
      Mg[((size_t)(b*512) + cb*128 + c)*128 + h*16 + l] = f2bf(dot);
    }
  }
}

// ---------------- attn2 probs: 128x128 q-GEMM (2 heads) + MFMA dots + softmax -> P bf16 ----------------
// LDS: staging dbuf 0..65536. Epilogue aliases staging: qt0 [128][72] @0, qt1 @18432 (->36864).
// Above staging: khs [2][16][72] @65536 (->70144), ssq [2][128] @70144 (->71168).
__global__ __launch_bounds__(256) void k_attn2p2(const unsigned short* __restrict__ wqx,
                                                 const unsigned short* __restrict__ xT,
                                                 const float* __restrict__ khatg,
                                                 unsigned short* __restrict__ Pg){
  int nb = blockIdx.x, hp = blockIdx.y, b = blockIdx.z;
  int n0 = nb*128;
  extern __shared__ char smr[];
  unsigned short* qt0 = (unsigned short*)smr;            // head hp*2   q-hat [128 n][72]
  unsigned short* qt1 = (unsigned short*)(smr + 18432);  // head hp*2+1
  unsigned short* khs = (unsigned short*)(smr + 65536);  // [2][16][72]
  float* ssq = (float*)(smr + 70144);                    // [2][128] rinv
  int t = threadIdx.x, lane = t&63, wave = t>>6;
  int wm = wave>>1, wn = wave&1, lr = lane&15, lq = lane>>4;
  // stage k-hat (0.125 folded) for both heads (outside staging region)
  for (int i = t; i < 2048; i += 256){
    int hh = i>>10, rem = i&1023;
    khs[hh*1152 + (rem>>6)*72 + (rem&63)] = f2bf(khatg[((size_t)(b*8 + hp*2 + hh))*1024 + rem]);
  }
  floatx4 acc[4][4];
  floatx4 zero = {0.f,0.f,0.f,0.f};
#pragma unroll
  for (int i = 0; i < 4; ++i) for (int j = 0; j < 4; ++j) acc[i][j] = zero;
  gemm128_db(wqx + (size_t)(hp*128)*512, wqx + (size_t)(hp*128 + 64)*512,
             xT + ((size_t)(b*4096 + n0))*512, smr, acc);
  // per-head column inverse norms (wave wm covers head wm's 64 rows)
#pragma unroll
  for (int nt = 0; nt < 4; ++nt){
    float s = 0.f;
#pragma unroll
    for (int mt = 0; mt < 4; ++mt)
#pragma unroll
      for (int r = 0; r < 4; ++r) s += acc[mt][nt][r]*acc[mt][nt][r];
    s += __shfl_xor(s, 16); s += __shfl_xor(s, 32);
    if (lq == 0) ssq[wm*128 + wn*64 + nt*16 + lr] = 1.f / fmaxf(sqrtf(s), 1e-12f);
  }
  __syncthreads();
  // q-hat tiles to LDS transposed [n][d], norm folded
  unsigned short* qtr = wm ? qt1 : qt0;
#pragma unroll
  for (int nt = 0; nt < 4; ++nt){
    int col = wn*64 + nt*16 + lr;
    float rinv = ssq[wm*128 + col];
#pragma unroll
    for (int mt = 0; mt < 4; ++mt){
      unsigned short tmp[4] __attribute__((aligned(8)));
#pragma unroll
      for (int r = 0; r < 4; ++r) tmp[r] = f2bf(acc[mt][nt][r]*rinv);
      *(short4_t*)&qtr[col*72 + mt*16 + lq*4] = *(short4_t*)tmp;
    }
  }
  __syncthreads();
  // S^T[n][l]: wave handles head wm, n-half wn (4 m-tiles), K=64
  floatx4 sl[4];
#pragma unroll
  for (int i = 0; i < 4; ++i) sl[i] = zero;
  unsigned short* qsrc = wm ? qt1 : qt0;
#pragma unroll
  for (int ks = 0; ks < 2; ++ks){
    bf16x8 bb = *(const bf16x8*)&khs[wm*1152 + lr*72 + ks*32 + lq*8];
#pragma unroll
    for (int i = 0; i < 4; ++i){
      bf16x8 aa = *(const bf16x8*)&qsrc[((wn*4 + i)*16 + lr)*72 + ks*32 + lq*8];
      sl[i] = __builtin_amdgcn_mfma_f32_16x16x32_bf16(aa, bb, sl[i], 0, 0, 0);
    }
  }
  int h = hp*2 + wm;
#pragma unroll
  for (int i = 0; i < 4; ++i){
    float p[4], s[4];
#pragma unroll
    for (int r = 0; r < 4; ++r){ p[r] = __expf(sl[i][r]); s[r] = p[r]; }
#pragma unroll
    for (int r = 0; r < 4; ++r){
      s[r] += __shfl_xor(s[r], 1);
      s[r] += __shfl_xor(s[r], 2);
      s[r] += __shfl_xor(s[r], 4);
      s[r] += __shfl_xor(s[r], 8);
    }
    int nbase = wn*64 + i*16 + lq*4;
#pragma unroll
    for (int r = 0; r < 4; ++r)
      Pg[((size_t)(b*4096 + n0 + nbase + r))*128 + h*16 + lr] = f2bf(p[r]/s[r]);
  }
}

// ---------------- out = M @ P + bias: 64x128 tile, K=128 ----------------
__global__ __launch_bounds__(256) void k_out(const unsigned short* __restrict__ Mg,
                                             const unsigned short* __restrict__ Pg,
                                             const float* __restrict__ biasf,
                                             void* __restrict__ outv, const int* __restrict__ flag){
  int nb = blockIdx.x, cb = blockIdx.y, b = blockIdx.z;
  int n0 = nb*128, c0 = cb*64;
  extern __shared__ char smr[];
  unsigned short* At = (unsigned short*)smr;   // [64][136]
  unsigned short* Bt = At + 64*136;            // [128][136]
  int t = threadIdx.x, lane = t&63, wave = t>>6;
  int wm = wave>>1, wn = wave&1, lr = lane&15, lq = lane>>4;
#pragma unroll
  for (int i = 0; i < 4; ++i){ int ch = i*256 + t; int r = ch>>4, p8 = (ch&15)*8;
    *(short8_t*)&At[r*136 + p8] = *(const short8_t*)&Mg[((size_t)(b*512 + c0 + r))*128 + p8]; }
#pragma unroll
  for (int i = 0; i < 8; ++i){ int ch = i*256 + t; int r = ch>>4, p8 = (ch&15)*8;
    *(short8_t*)&Bt[r*136 + p8] = *(const short8_t*)&Pg[((size_t)(b*4096 + n0 + r))*128 + p8]; }
  __syncthreads();
  floatx4 acc[2][4];
  floatx4 zero = {0.f,0.f,0.f,0.f};
#pragma unroll
  for (int i = 0; i < 2; ++i) for (int j = 0; j < 4; ++j) acc[i][j] = zero;
#pragma unroll
  for (int ks = 0; ks < 4; ++ks){
    bf16x8 a0 = *(const bf16x8*)&At[(wm*32 + lr)*136 + ks*32 + lq*8];
    bf16x8 a1 = *(const bf16x8*)&At[(wm*32 + 16 + lr)*136 + ks*32 + lq*8];
#pragma unroll
    for (int nt = 0; nt < 4; ++nt){
      bf16x8 bb = *(const bf16x8*)&Bt[(wn*64 + nt*16 + lr)*136 + ks*32 + lq*8];
      acc[0][nt] = __builtin_amdgcn_mfma_f32_16x16x32_bf16(a0, bb, acc[0][nt], 0, 0, 0);
      acc[1][nt] = __builtin_amdgcn_mfma_f32_16x16x32_bf16(a1, bb, acc[1][nt], 0, 0, 0);
    }
  }
  __syncthreads();
  float* ct = (float*)smr;  // [64][132] f32
#pragma unroll
  for (int mt = 0; mt < 2; ++mt)
#pragma unroll
    for (int nt = 0; nt < 4; ++nt)
#pragma unroll
      for (int r = 0; r < 4; ++r){
        int row = wm*32 + mt*16 + lq*4 + r;
        ct[row*132 + wn*64 + nt*16 + lr] = acc[mt][nt][r] + biasf[c0 + row];
      }
  __syncthreads();
  if (*flag){
    float* of = (float*)outv;
#pragma unroll
    for (int i = 0; i < 8; ++i){ int ch = i*256 + t; int r = ch>>5, c4 = (ch&31)*4;
      *(float4*)&of[((size_t)(b*512 + c0 + r))*4096 + n0 + c4] = *(float4*)&ct[r*132 + c4]; }
  } else {
    unsigned short* ob = (unsigned short*)outv;
#pragma unroll
    for (int i = 0; i < 4; ++i){ int ch = i*256 + t; int r = ch>>4, c8 = (ch&15)*8;
      unsigned short tmp[8] __attribute__((aligned(16)));
#pragma unroll
      for (int j = 0; j < 8; ++j) tmp[j] = f2bf(ct[r*132 + c8 + j]);
      *(short8_t*)&ob[((size_t)(b*512 + c0 + r))*4096 + n0 + c8] = *(short8_t*)tmp; }
  }
}

extern "C" void kernel_launch(void* const* d_in, const int* in_sizes, int n_in,
                              void* d_out, int out_size, void* d_ws, size_t ws_size,
                              hipStream_t stream){
  (void)in_sizes; (void)n_in; (void)out_size; (void)ws_size;
  char* ws = (char*)d_ws;
  int* flag              = (int*)ws;
  unsigned short* xT     = (unsigned short*)(ws + OFF_XT);
  unsigned short* Pg     = (unsigned short*)(ws + OFF_KVX);              // [8][4096][128] bf16 = 8 MB
  unsigned short* Mg     = (unsigned short*)(ws + OFF_KVX + 8388608ull); // [8][512][128] bf16
  unsigned short* wkvx   = (unsigned short*)(ws + OFF_WKVX);
  unsigned short* wqx    = (unsigned short*)(ws + OFF_WQX);
  unsigned short* wkvl   = (unsigned short*)(ws + OFF_WKVL);
  unsigned short* wproj  = (unsigned short*)(ws + OFF_WPROJ);
  float* biasf = (float*)(ws + OFF_BIAS);
  float* qlh   = (float*)(ws + OFF_QLH);
  float* gnum  = (float*)(ws + OFF_GNUM);
  float* gden  = (float*)(ws + OFF_GDEN);
  float* khat  = (float*)(ws + OFF_KHAT);

  k_sniff<<<1, 256, 0, stream>>>((const unsigned short*)d_in[0], flag);

  // xt + weight-prep + bias + ql + gnum/gden zero, one launch
  k_mega1<<<5130, 256, 29760, stream>>>(d_in[0], d_in[1], d_in[2],
                                        d_in[3], d_in[4], d_in[5], d_in[6], d_in[2],
                                        d_in[7], xT, wkvx, biasf, qlh, gnum, flag);

  k_kvattn1<<<dim3(32, 8, 8), 256, 68608, stream>>>(wkvx, xT, qlh, gnum, gden);
  k_kvlnm<<<dim3(8, 8), 256, 76352, stream>>>(wkvl, wproj, gnum, gden, khat, Mg);
  k_attn2p2<<<dim3(32, 4, 8), 256, 71168, stream>>>(wqx, xT, khat, Pg);
  k_out<<<dim3(32, 8, 8), 256, 52224, stream>>>(Mg, Pg, biasf, d_out, flag);
}

// Round 8
// 287.009 us; speedup vs baseline: 1.0980x; 1.0980x over previous
//
#include <hip/hip_runtime.h>

// LatentMixer on MI355X. bf16-MFMA pipeline with runtime input-dtype sniffing.
// B=8, C=512, HW=4096, L=16, heads=8, d=64, scale=0.125, eps=1e-12.
// R2: out = (w_proj@blockdiag(V)) @ P + bias (algebraic fusion).
// R3: attn1 fused into kv-GEMM epilogue; 128x128 tiles.
// R4: global_load_lds width=16 staging.  R5: XOR-swizzled glld layout.
// R7: native __bf16 cast f2bf.
// R8: dbuf prefetch gemm (kvattn1 90->66us).  R9: setprio(1) around dbuf compute.
// R10: attn2p2 on dbuf gemm (281.7us best).
// R11 (REVERTED): mega-fusion cost 33us — oversized LDS cut xt occupancy 8->5/CU;
//      kvlnm's 64-block grid idled 75% of CUs. Lesson: never trade occupancy for launches.
// R12: R10 config + gnum/gden zeroing folded into k_prep (no-LDS blocks, replaces memset).

typedef __bf16 bf16x8 __attribute__((ext_vector_type(8)));
typedef float floatx4 __attribute__((ext_vector_type(4)));
typedef short short8_t __attribute__((ext_vector_type(8)));
typedef short short4_t __attribute__((ext_vector_type(4)));

#define DEV __device__ __forceinline__

DEV float bf2f(unsigned short u){ union{unsigned int i; float f;} v; v.i = ((unsigned int)u)<<16; return v.f; }
DEV unsigned short f2bf(float f){
  __bf16 h = (__bf16)f;                  // RTNE; compiler packs pairs into v_cvt_pk_bf16_f32
  unsigned short u; __builtin_memcpy(&u, &h, 2); return u;
}

// async global->LDS, 16 B per lane; LDS dest = base + lane*16 (wave-uniform base!)
DEV void glds16(const void* g, void* l){
  __builtin_amdgcn_global_load_lds((const __attribute__((address_space(1))) void*)g,
                                   (__attribute__((address_space(3))) void*)l, 16, 0, 0);
}

// ---------------- workspace layout (bytes) ----------------
#define OFF_XT     256ull                          // xT bf16 [8][4096][512]
#define OFF_KVX    (OFF_XT + 33554432ull)          // region reused: Pg bf16 [8][4096][128] + Mg
#define OFF_WKVX   (OFF_KVX + 67108864ull)         // w_kv_x bf16   (weights contiguous from here)
#define OFF_WQX    (OFF_WKVX + 1048576ull)         // w_q_x bf16
#define OFF_WKVL   (OFF_WQX + 524288ull)           // w_kv_lat bf16
#define OFF_WPROJ  (OFF_WKVL + 1048576ull)         // w_proj bf16
#define OFF_WQLAT  (OFF_WPROJ + 524288ull)         // w_q_lat bf16
#define OFF_LATF   (OFF_WQLAT + 524288ull)         // latents f32 [512][16]
#define OFF_BIAS   (OFF_LATF + 32768ull)           // bias f32 [512]
#define OFF_QLH    (OFF_BIAS + 4096ull)            // ql-hat f32 [h][l][64] (0.125 folded)
#define OFF_GNUM   (OFF_QLH + 32768ull)            // attn1 numerator f32 [b][h][l][64]
#define OFF_GDEN   (OFF_GNUM + 524288ull)          // attn1 denominator f32 [b][h][l] (contig after gnum)
#define OFF_KVL    (OFF_GDEN + 4096ull)            // kvl f32 [b][1024][16]
#define OFF_KHAT   (OFF_KVL + 524288ull)           // k-hat f32 [b][h][l][64] (0.125 folded)
#define OFF_GVL    (OFF_KHAT + 524288ull)          // vl f32 [b][h][l][64]

// ---------------- dtype sniff ----------------
__global__ void k_sniff(const unsigned short* __restrict__ x, int* flag){
  int t = threadIdx.x;
  int m = 0;
  for (int i = t; i < 4096; i += 256){ int e = (x[i]>>7)&0xFF; m = (e>m)?e:m; }
  __shared__ int red[256];
  red[t] = m; __syncthreads();
  for (int s = 128; s > 0; s >>= 1){ if (t < s) red[t] = (red[t+s]>red[t])?red[t+s]:red[t]; __syncthreads(); }
  if (t == 0) flag[0] = (red[0] > 150) ? 1 : 0;   // 1 => fp32 inputs, 0 => bf16 inputs
}

// ---------------- fused prep: 5 weight converts + latents + bias + gnum/gden zero ----------------
__global__ __launch_bounds__(256) void k_prep(const void* s0, const void* s1, const void* s2,
                                              const void* s3, const void* s4,
                                              const void* slat, const void* sbias,
                                              unsigned short* __restrict__ wdst,
                                              float* __restrict__ latf, float* __restrict__ biasf,
                                              float* __restrict__ zro,
                                              const int* __restrict__ flag){
  int b = blockIdx.x, t = threadIdx.x;
  int isf = *flag;
  if (b < 896){
    int e = b*2048 + t*8;
    const void* src; int off;
    if (e < 524288)      { src = s0; off = e; }
    else if (e < 786432) { src = s1; off = e - 524288; }
    else if (e < 1310720){ src = s2; off = e - 786432; }
    else if (e < 1572864){ src = s3; off = e - 1310720; }
    else                 { src = s4; off = e - 1572864; }
    if (isf){
      const float* s = (const float*)src + off;
      float4 v0 = *(const float4*)(s);
      float4 v1 = *(const float4*)(s+4);
      unsigned short tmp[8] __attribute__((aligned(16)));
      tmp[0]=f2bf(v0.x); tmp[1]=f2bf(v0.y); tmp[2]=f2bf(v0.z); tmp[3]=f2bf(v0.w);
      tmp[4]=f2bf(v1.x); tmp[5]=f2bf(v1.y); tmp[6]=f2bf(v1.z); tmp[7]=f2bf(v1.w);
      *(short8_t*)&wdst[e] = *(short8_t*)tmp;
    } else {
      *(short8_t*)&wdst[e] = *(const short8_t*)((const unsigned short*)src + off);
    }
  } else if (b < 900){
    int i = (b-896)*2048 + t*8;
#pragma unroll
    for (int j = 0; j < 8; ++j)
      latf[i+j] = isf ? ((const float*)slat)[i+j] : bf2f(((const unsigned short*)slat)[i+j]);
  } else if (b == 900){
    if (t < 512) biasf[t] = isf ? ((const float*)sbias)[t] : bf2f(((const unsigned short*)sbias)[t]);
    if (t + 256 < 512) biasf[t+256] = isf ? ((const float*)sbias)[t+256] : bf2f(((const unsigned short*)sbias)[t+256]);
  } else {
    // zero gnum+gden: 528384 B = 33024 float4 = 129 blocks x 256 thr exactly
    int i = (b-901)*256 + t;
    float4 z; z.x=0.f; z.y=0.f; z.z=0.f; z.w=0.f;
    ((float4*)zro)[i] = z;
  }
}

// ---------------- transpose x[b][c][n] -> xT[b][n][c] (bf16) ----------------
__global__ __launch_bounds__(256) void k_xt(const void* __restrict__ xraw, unsigned short* __restrict__ xT,
                                            const int* __restrict__ flag){
  int nb = blockIdx.x, cb = blockIdx.y, b = blockIdx.z;
  int n0 = nb*64, c0 = cb*64;
  __shared__ unsigned short tile[64][72];   // XOR-swizzled columns: col = n ^ (((row>>3)&7)<<3)
  int t = threadIdx.x;
  if (*flag){
    const float* xp = (const float*)xraw;
#pragma unroll
    for (int i = 0; i < 4; ++i){
      int ch = i*256 + t; int c = ch>>4, n4 = (ch&15)*4;
      float4 v = *(const float4*)&xp[((size_t)(b*512 + c0 + c))*4096 + n0 + n4];
      int cc = n4 ^ (((c>>3)&7)<<3);
      tile[c][cc+0]=f2bf(v.x); tile[c][cc+1]=f2bf(v.y); tile[c][cc+2]=f2bf(v.z); tile[c][cc+3]=f2bf(v.w);
    }
  } else {
    const unsigned short* xp = (const unsigned short*)xraw;
#pragma unroll
    for (int i = 0; i < 2; ++i){
      int ch = i*256 + t; int c = ch>>3, n8 = (ch&7)*8;
      *(short8_t*)&tile[c][n8 ^ (((c>>3)&7)<<3)] =
        *(const short8_t*)&xp[((size_t)(b*512 + c0 + c))*4096 + n0 + n8];
    }
  }
  __syncthreads();
#pragma unroll
  for (int i = 0; i < 2; ++i){
    int ch = i*256 + t; int n = ch>>3, c8 = (ch&7)*8;
    unsigned short tmp[8] __attribute__((aligned(16)));
#pragma unroll
    for (int j = 0; j < 8; ++j){
      int c = c8 + j;
      tmp[j] = tile[c][n ^ (((c>>3)&7)<<3)];
    }
    *(short8_t*)&xT[((size_t)(b*4096 + n0 + n))*512 + c0 + c8] = *(short8_t*)tmp;
  }
}

// ---------------- ql = w_q_lat @ latents + normalize -> qlhat [h][l][64], 0.125 folded ----------------
__global__ __launch_bounds__(256) void k_ql(const unsigned short* __restrict__ wqlat,
                                            const float* __restrict__ latf, float* __restrict__ qlh){
  int h = blockIdx.x, o0 = h*64;
  extern __shared__ char smr[];
  float* latb = (float*)smr;                          // [128][16] = 8192
  unsigned short* wt = (unsigned short*)(smr + 8192); // [64][136] = 17408
  float* qbuf = (float*)(smr + 8192 + 17408);         // [64][16] = 4096
  float* rinv = (float*)(smr + 8192 + 17408 + 4096);  // [16]
  int t = threadIdx.x;
  int o = t>>2, l4 = (t&3)*4;
  float acc[4] = {0.f,0.f,0.f,0.f};
  for (int kk = 0; kk < 512; kk += 128){
    __syncthreads();
#pragma unroll
    for (int j = 0; j < 8; ++j){ int i = j*256 + t; latb[i] = latf[kk*16 + i]; }
#pragma unroll
    for (int j = 0; j < 4; ++j){ int ch = j*256 + t; int r = ch>>4, kc = (ch&15)*8;
      *(short8_t*)&wt[r*136 + kc] = *(const short8_t*)&wqlat[(size_t)(o0+r)*512 + kk + kc]; }
    __syncthreads();
    for (int k = 0; k < 128; ++k){
      float w = bf2f(wt[o*136 + k]);
      const float* lr = &latb[k*16 + l4];
#pragma unroll
      for (int j = 0; j < 4; ++j) acc[j] += w*lr[j];
    }
  }
#pragma unroll
  for (int j = 0; j < 4; ++j) qbuf[o*16 + l4 + j] = acc[j];
  __syncthreads();
  if (t < 16){
    float ss = 0.f;
    for (int oo = 0; oo < 64; ++oo){ float v = qbuf[oo*16 + t]; ss += v*v; }
    rinv[t] = 0.125f / fmaxf(sqrtf(ss), 1e-12f);
  }
  __syncthreads();
#pragma unroll
  for (int j = 0; j < 4; ++j) qlh[(h*16 + l4 + j)*64 + o] = acc[j]*rinv[l4 + j];
}

// ---------------- shared staging helper (XOR-swizzled k8 within row) ----------------
DEV void stage_ab(const unsigned short* __restrict__ Ap0, const unsigned short* __restrict__ Ap1,
                  const unsigned short* __restrict__ Bp, int kk,
                  unsigned short* At, unsigned short* Bt, int wave, int rsub, int koff){
#pragma unroll
  for (int c2 = 0; c2 < 4; ++c2){
    int chunk = wave*4 + c2;           // 0..15, wave-uniform
    int row = chunk*8 + rsub;
    const unsigned short* gp = (chunk < 8) ? (Ap0 + (size_t)row*512 + kk + koff)
                                           : (Ap1 + (size_t)(row-64)*512 + kk + koff);
    glds16(gp, At + chunk*512);
  }
#pragma unroll
  for (int c2 = 0; c2 < 4; ++c2){
    int chunk = wave*4 + c2;
    int row = chunk*8 + rsub;
    glds16(Bp + (size_t)row*512 + kk + koff, Bt + chunk*512);
  }
}

// ---------------- 128x128 GEMM, double-buffered prefetch (64KB staging) ----------------
// 2-phase: stage(k+1) issued BEFORE compute(k); one barrier per step. setprio(1) around
// compute phase: dbuf creates stage-issue/MFMA wave role split -> scheduler favors compute.
DEV void gemm128_db(const unsigned short* __restrict__ Ap0, const unsigned short* __restrict__ Ap1,
                    const unsigned short* __restrict__ Bp,
                    char* smr, floatx4 (&acc)[4][4]){
  unsigned short* At0 = (unsigned short*)smr;
  unsigned short* Bt0 = (unsigned short*)(smr + 16384);
  unsigned short* At1 = (unsigned short*)(smr + 32768);
  unsigned short* Bt1 = (unsigned short*)(smr + 49152);
  int t = threadIdx.x, lane = t&63, wave = t>>6;
  int wm = wave>>1, wn = wave&1, lr = lane&15, lq = lane>>4;
  int rsub = lane>>3;                 // 0..7: row within 8-row chunk
  int koff = ((lane&7) ^ rsub)*8;     // swizzled global k8 slot (shorts)
  int sw = lr&7;                      // read-side XOR factor
  stage_ab(Ap0, Ap1, Bp, 0, At0, Bt0, wave, rsub, koff);
  __syncthreads();                    // drains vmcnt(0): tile 0 resident
  for (int kk = 0; kk < 512; kk += 64){
    int cur = (kk>>6)&1;
    unsigned short* Ac = cur ? At1 : At0;
    unsigned short* Bc = cur ? Bt1 : Bt0;
    if (kk < 448){                    // issue next tile's loads FIRST (overlap with compute)
      stage_ab(Ap0, Ap1, Bp, kk+64, cur ? At0 : At1, cur ? Bt0 : Bt1, wave, rsub, koff);
    }
    __builtin_amdgcn_s_setprio(1);
#pragma unroll
    for (int ks = 0; ks < 2; ++ks){
      int vo = ((ks*4 + lq) ^ sw)*8;
      bf16x8 a[4], b[4];
#pragma unroll
      for (int mt = 0; mt < 4; ++mt) a[mt] = *(const bf16x8*)&Ac[(wm*64 + mt*16 + lr)*64 + vo];
#pragma unroll
      for (int nt = 0; nt < 4; ++nt) b[nt] = *(const bf16x8*)&Bc[(wn*64 + nt*16 + lr)*64 + vo];
#pragma unroll
      for (int mt = 0; mt < 4; ++mt)
#pragma unroll
        for (int nt = 0; nt < 4; ++nt)
          acc[mt][nt] = __builtin_amdgcn_mfma_f32_16x16x32_bf16(a[mt], b[nt], acc[mt][nt], 0, 0, 0);
    }
    __builtin_amdgcn_s_setprio(0);
    __syncthreads();                  // next tile's writes complete + all reads of cur done
  }
}

// ---------------- fused kv-GEMM + attn1: M-tile = [k_h(64); v_h(64)], N=128 positions ----------------
// LDS: staging dbuf 0..65536. Epilogue aliases staging: kt [128][72] @0 (18432),
// vt [64][136] @18432 (->35840), pt [16][136] @35840 (->40192).
// Above staging: qls [16][72] @65536 (->67840), ssq @67840 (->68352), wred @68352 (->68608).
__global__ __launch_bounds__(256) void k_kvattn1(const unsigned short* __restrict__ wkvx,
                                                 const unsigned short* __restrict__ xT,
                                                 const float* __restrict__ qlh2,
                                                 float* __restrict__ gnum, float* __restrict__ gden){
  int nb = blockIdx.x, h = blockIdx.y, b = blockIdx.z;
  int n0 = nb*128;
  extern __shared__ char smr[];
  unsigned short* kt  = (unsigned short*)smr;            // [128 n][72] k-hat, d contiguous
  unsigned short* vt  = (unsigned short*)(smr + 18432);  // [64 d][136]
  unsigned short* pt  = (unsigned short*)(smr + 35840);  // [16 l][136] p bf16
  unsigned short* qls = (unsigned short*)(smr + 65536);  // [16 l][72] 0.125*q-hat
  float* ssq  = (float*)(smr + 67840);                   // [128] rinv
  float* wred = (float*)(smr + 68352);                   // [4][16]
  int t = threadIdx.x, lane = t&63, wave = t>>6;
  int wm = wave>>1, wn = wave&1, lr = lane&15, lq = lane>>4;
  // stage 0.125*q-hat [16][72] (outside staging region; before GEMM to overlap)
  for (int i = t; i < 1024; i += 256) qls[(i>>6)*72 + (i&63)] = f2bf(qlh2[(size_t)h*1024 + i]);
  floatx4 acc[4][4];
  floatx4 zero = {0.f,0.f,0.f,0.f};
#pragma unroll
  for (int i = 0; i < 4; ++i) for (int j = 0; j < 4; ++j) acc[i][j] = zero;
  gemm128_db(wkvx + (size_t)(h*64)*512, wkvx + (size_t)(512 + h*64)*512,
             xT + ((size_t)(b*4096 + n0))*512, smr, acc);
  if (wm == 0){
    // k column inverse norms from f32 accumulators
#pragma unroll
    for (int nt = 0; nt < 4; ++nt){
      float s = 0.f;
#pragma unroll
      for (int mt = 0; mt < 4; ++mt)
#pragma unroll
        for (int r = 0; r < 4; ++r) s += acc[mt][nt][r]*acc[mt][nt][r];
      s += __shfl_xor(s, 16); s += __shfl_xor(s, 32);
      if (lq == 0) ssq[wn*64 + nt*16 + lr] = 1.f / fmaxf(sqrtf(s), 1e-12f);
    }
  } else {
    // v tile to LDS [d][n]
#pragma unroll
    for (int mt = 0; mt < 4; ++mt)
#pragma unroll
      for (int nt = 0; nt < 4; ++nt){
        int col = wn*64 + nt*16 + lr;
#pragma unroll
        for (int r = 0; r < 4; ++r) vt[(mt*16 + lq*4 + r)*136 + col] = f2bf(acc[mt][nt][r]);
      }
  }
  __syncthreads();
  if (wm == 0){
    // k-hat tile to LDS transposed [n][d], norm folded
#pragma unroll
    for (int nt = 0; nt < 4; ++nt){
      int col = wn*64 + nt*16 + lr;
      float rinv = ssq[col];
#pragma unroll
      for (int mt = 0; mt < 4; ++mt){
        unsigned short tmp[4] __attribute__((aligned(8)));
#pragma unroll
        for (int r = 0; r < 4; ++r) tmp[r] = f2bf(acc[mt][nt][r]*rinv);
        *(short4_t*)&kt[col*72 + mt*16 + lq*4] = *(short4_t*)tmp;
      }
    }
  }
  __syncthreads();
  // S^T[n][l] via MFMA: A = kt rows n, B = qls rows l, K=64
  floatx4 sl[2]; sl[0] = zero; sl[1] = zero;
#pragma unroll
  for (int ks = 0; ks < 2; ++ks){
    bf16x8 bb = *(const bf16x8*)&qls[lr*72 + ks*32 + lq*8];
#pragma unroll
    for (int i = 0; i < 2; ++i){
      bf16x8 aa = *(const bf16x8*)&kt[((wave*2 + i)*16 + lr)*72 + ks*32 + lq*8];
      sl[i] = __builtin_amdgcn_mfma_f32_16x16x32_bf16(aa, bb, sl[i], 0, 0, 0);
    }
  }
  // p = exp(s) (|s| <= 0.125); den partials; p to LDS [l][n]
  float dp = 0.f;
  float pv[2][4];
#pragma unroll
  for (int i = 0; i < 2; ++i)
#pragma unroll
    for (int r = 0; r < 4; ++r){ float p = __expf(sl[i][r]); pv[i][r] = p; dp += p; }
  dp += __shfl_xor(dp, 16); dp += __shfl_xor(dp, 32);
  if (lq == 0) wred[wave*16 + lr] = dp;
#pragma unroll
  for (int i = 0; i < 2; ++i){
    unsigned short tmp[4] __attribute__((aligned(8)));
#pragma unroll
    for (int r = 0; r < 4; ++r) tmp[r] = f2bf(pv[i][r]);
    *(short4_t*)&pt[lr*136 + (wave*2 + i)*16 + lq*4] = *(short4_t*)tmp;
  }
  __syncthreads();
  int bh = b*8 + h;
  if (t < 16) atomicAdd(&gden[bh*16 + t], wred[t] + wred[16+t] + wred[32+t] + wred[48+t]);
  // num^T[d][l] via MFMA: A = vt rows d (wave*16 block), B = pt rows l, K=128
  floatx4 nacc = zero;
#pragma unroll
  for (int ks = 0; ks < 4; ++ks){
    bf16x8 aa = *(const bf16x8*)&vt[(wave*16 + lr)*136 + ks*32 + lq*8];
    bf16x8 bb = *(const bf16x8*)&pt[lr*136 + ks*32 + lq*8];
    nacc = __builtin_amdgcn_mfma_f32_16x16x32_bf16(aa, bb, nacc, 0, 0, 0);
  }
  float* gp = &gnum[((size_t)bh*16 + lr)*64 + wave*16 + lq*4];
#pragma unroll
  for (int r = 0; r < 4; ++r) atomicAdd(&gp[r], nacc[r]);
}

// ---------------- kvl = w_kv_lat @ (num/den), f32 [b][o][l] ----------------
__global__ __launch_bounds__(256) void k_kvl(const unsigned short* __restrict__ wkvl,
                                             const float* __restrict__ gnum, const float* __restrict__ gden,
                                             float* __restrict__ kvl){
  int ob = blockIdx.x, b = blockIdx.y;
  extern __shared__ char smr[];
  float* latb = (float*)smr;                         // [512][16]
  unsigned short* wt = (unsigned short*)(smr + 32768); // [16][136]
  int t = threadIdx.x;
  for (int i = t; i < 8192; i += 256){
    int c = i>>4, l = i&15;
    int h = c>>6, d = c&63;
    int bh = b*8 + h;
    latb[i] = gnum[((size_t)(bh*16 + l))*64 + d] / gden[bh*16 + l];
  }
  int o = t>>4, l = t&15;
  int o0 = ob*16;
  float acc = 0.f;
  for (int kk = 0; kk < 512; kk += 128){
    __syncthreads();
    { int r = t>>4, kc = (t&15)*8;
      *(short8_t*)&wt[r*136 + kc] = *(const short8_t*)&wkvl[(size_t)(o0+r)*512 + kk + kc]; }
    __syncthreads();
    for (int k = 0; k < 128; ++k) acc += bf2f(wt[o*136 + k]) * latb[(kk+k)*16 + l];
  }
  kvl[((size_t)(b*1024 + o0 + o))*16 + l] = acc;
}

// normalize kl per (b,h,l); khat gets 0.125 folded; gvl raw
__global__ void k_klnorm(const float* __restrict__ kvl, float* __restrict__ khat, float* __restrict__ gvl){
  int l = blockIdx.x, h = blockIdx.y, b = blockIdx.z, d = threadIdx.x;
  float kl = kvl[((size_t)(b*1024 + h*64 + d))*16 + l];
  float vl = kvl[((size_t)(b*1024 + 512 + h*64 + d))*16 + l];
  float ss = kl*kl;
  for (int off = 32; off; off >>= 1) ss += __shfl_xor(ss, off);
  float inv = 0.125f / fmaxf(sqrtf(ss), 1e-12f);
  size_t o = ((size_t)((b*8+h)*16 + l))*64 + d;
  khat[o] = kl*inv;
  gvl[o] = vl;
}

// ---------------- Mmat: M[b][c][h*16+l] = sum_d wproj[c][h*64+d] * vl[b][h][l][d] ----------------
__global__ __launch_bounds__(256) void k_mmat(const unsigned short* __restrict__ wproj,
                                              const float* __restrict__ gvl,
                                              unsigned short* __restrict__ Mg){
  int cb = blockIdx.x, h = blockIdx.y, b = blockIdx.z;
  __shared__ unsigned short wt[128*68];
  int t = threadIdx.x;
#pragma unroll
  for (int i = 0; i < 4; ++i){ int ch = i*256 + t; int c = ch>>3, d8 = (ch&7)*8;
    *(short8_t*)&wt[c*68 + d8] = *(const short8_t*)&wproj[(size_t)(cb*128 + c)*512 + h*64 + d8]; }
  int l = t&15, cq = t>>4;
  float v[64];
  const float* vp = &gvl[((size_t)(b*8+h)*16 + l)*64];
#pragma unroll
  for (int j = 0; j < 16; ++j){ float4 f = *(const float4*)&vp[j*4];
    v[j*4+0]=f.x; v[j*4+1]=f.y; v[j*4+2]=f.z; v[j*4+3]=f.w; }
  __syncthreads();
#pragma unroll
  for (int c8 = 0; c8 < 8; ++c8){
    int c = cq*8 + c8;
    float dot = 0.f;
#pragma unroll
    for (int d = 0; d < 64; ++d) dot += bf2f(wt[c*68 + d]) * v[d];
    Mg[((size_t)(b*512) + cb*128 + c)*128 + h*16 + l] = f2bf(dot);
  }
}

// ---------------- attn2 probs: 128x128 q-GEMM (2 heads) + MFMA dots + softmax -> P bf16 ----------------
// LDS: staging dbuf 0..65536. Epilogue aliases staging: qt0 [128][72] @0, qt1 @18432 (->36864).
// Above staging: khs [2][16][72] @65536 (->70144), ssq [2][128] @70144 (->71168).
__global__ __launch_bounds__(256) void k_attn2p2(const unsigned short* __restrict__ wqx,
                                                 const unsigned short* __restrict__ xT,
                                                 const float* __restrict__ khatg,
                                                 unsigned short* __restrict__ Pg){
  int nb = blockIdx.x, hp = blockIdx.y, b = blockIdx.z;
  int n0 = nb*128;
  extern __shared__ char smr[];
  unsigned short* qt0 = (unsigned short*)smr;            // head hp*2   q-hat [128 n][72]
  unsigned short* qt1 = (unsigned short*)(smr + 18432);  // head hp*2+1
  unsigned short* khs = (unsigned short*)(smr + 65536);  // [2][16][72]
  float* ssq = (float*)(smr + 70144);                    // [2][128] rinv
  int t = threadIdx.x, lane = t&63, wave = t>>6;
  int wm = wave>>1, wn = wave&1, lr = lane&15, lq = lane>>4;
  // stage k-hat (0.125 folded) for both heads (outside staging region)
  for (int i = t; i < 2048; i += 256){
    int hh = i>>10, rem = i&1023;
    khs[hh*1152 + (rem>>6)*72 + (rem&63)] = f2bf(khatg[((size_t)(b*8 + hp*2 + hh))*1024 + rem]);
  }
  floatx4 acc[4][4];
  floatx4 zero = {0.f,0.f,0.f,0.f};
#pragma unroll
  for (int i = 0; i < 4; ++i) for (int j = 0; j < 4; ++j) acc[i][j] = zero;
  gemm128_db(wqx + (size_t)(hp*128)*512, wqx + (size_t)(hp*128 + 64)*512,
             xT + ((size_t)(b*4096 + n0))*512, smr, acc);
  // per-head column inverse norms (wave wm covers head wm's 64 rows)
#pragma unroll
  for (int nt = 0; nt < 4; ++nt){
    float s = 0.f;
#pragma unroll
    for (int mt = 0; mt < 4; ++mt)
#pragma unroll
      for (int r = 0; r < 4; ++r) s += acc[mt][nt][r]*acc[mt][nt][r];
    s += __shfl_xor(s, 16); s += __shfl_xor(s, 32);
    if (lq == 0) ssq[wm*128 + wn*64 + nt*16 + lr] = 1.f / fmaxf(sqrtf(s), 1e-12f);
  }
  __syncthreads();
  // q-hat tiles to LDS transposed [n][d], norm folded
  unsigned short* qtr = wm ? qt1 : qt0;
#pragma unroll
  for (int nt = 0; nt < 4; ++nt){
    int col = wn*64 + nt*16 + lr;
    float rinv = ssq[wm*128 + col];
#pragma unroll
    for (int mt = 0; mt < 4; ++mt){
      unsigned short tmp[4] __attribute__((aligned(8)));
#pragma unroll
      for (int r = 0; r < 4; ++r) tmp[r] = f2bf(acc[mt][nt][r]*rinv);
      *(short4_t*)&qtr[col*72 + mt*16 + lq*4] = *(short4_t*)tmp;
    }
  }
  __syncthreads();
  // S^T[n][l]: wave handles head wm, n-half wn (4 m-tiles), K=64
  floatx4 sl[4];
#pragma unroll
  for (int i = 0; i < 4; ++i) sl[i] = zero;
  unsigned short* qsrc = wm ? qt1 : qt0;
#pragma unroll
  for (int ks = 0; ks < 2; ++ks){
    bf16x8 bb = *(const bf16x8*)&khs[wm*1152 + lr*72 + ks*32 + lq*8];
#pragma unroll
    for (int i = 0; i < 4; ++i){
      bf16x8 aa = *(const bf16x8*)&qsrc[((wn*4 + i)*16 + lr)*72 + ks*32 + lq*8];
      sl[i] = __builtin_amdgcn_mfma_f32_16x16x32_bf16(aa, bb, sl[i], 0, 0, 0);
    }
  }
  int h = hp*2 + wm;
#pragma unroll
  for (int i = 0; i < 4; ++i){
    float p[4], s[4];
#pragma unroll
    for (int r = 0; r < 4; ++r){ p[r] = __expf(sl[i][r]); s[r] = p[r]; }
#pragma unroll
    for (int r = 0; r < 4; ++r){
      s[r] += __shfl_xor(s[r], 1);
      s[r] += __shfl_xor(s[r], 2);
      s[r] += __shfl_xor(s[r], 4);
      s[r] += __shfl_xor(s[r], 8);
    }
    int nbase = wn*64 + i*16 + lq*4;
#pragma unroll
    for (int r = 0; r < 4; ++r)
      Pg[((size_t)(b*4096 + n0 + nbase + r))*128 + h*16 + lr] = f2bf(p[r]/s[r]);
  }
}

// ---------------- out = M @ P + bias: 64x128 tile, K=128 ----------------
__global__ __launch_bounds__(256) void k_out(const unsigned short* __restrict__ Mg,
                                             const unsigned short* __restrict__ Pg,
                                             const float* __restrict__ biasf,
                                             void* __restrict__ outv, const int* __restrict__ flag){
  int nb = blockIdx.x, cb = blockIdx.y, b = blockIdx.z;
  int n0 = nb*128, c0 = cb*64;
  extern __shared__ char smr[];
  unsigned short* At = (unsigned short*)smr;   // [64][136]
  unsigned short* Bt = At + 64*136;            // [128][136]
  int t = threadIdx.x, lane = t&63, wave = t>>6;
  int wm = wave>>1, wn = wave&1, lr = lane&15, lq = lane>>4;
#pragma unroll
  for (int i = 0; i < 4; ++i){ int ch = i*256 + t; int r = ch>>4, p8 = (ch&15)*8;
    *(short8_t*)&At[r*136 + p8] = *(const short8_t*)&Mg[((size_t)(b*512 + c0 + r))*128 + p8]; }
#pragma unroll
  for (int i = 0; i < 8; ++i){ int ch = i*256 + t; int r = ch>>4, p8 = (ch&15)*8;
    *(short8_t*)&Bt[r*136 + p8] = *(const short8_t*)&Pg[((size_t)(b*4096 + n0 + r))*128 + p8]; }
  __syncthreads();
  floatx4 acc[2][4];
  floatx4 zero = {0.f,0.f,0.f,0.f};
#pragma unroll
  for (int i = 0; i < 2; ++i) for (int j = 0; j < 4; ++j) acc[i][j] = zero;
#pragma unroll
  for (int ks = 0; ks < 4; ++ks){
    bf16x8 a0 = *(const bf16x8*)&At[(wm*32 + lr)*136 + ks*32 + lq*8];
    bf16x8 a1 = *(const bf16x8*)&At[(wm*32 + 16 + lr)*136 + ks*32 + lq*8];
#pragma unroll
    for (int nt = 0; nt < 4; ++nt){
      bf16x8 bb = *(const bf16x8*)&Bt[(wn*64 + nt*16 + lr)*136 + ks*32 + lq*8];
      acc[0][nt] = __builtin_amdgcn_mfma_f32_16x16x32_bf16(a0, bb, acc[0][nt], 0, 0, 0);
      acc[1][nt] = __builtin_amdgcn_mfma_f32_16x16x32_bf16(a1, bb, acc[1][nt], 0, 0, 0);
    }
  }
  __syncthreads();
  float* ct = (float*)smr;  // [64][132] f32
#pragma unroll
  for (int mt = 0; mt < 2; ++mt)
#pragma unroll
    for (int nt = 0; nt < 4; ++nt)
#pragma unroll
      for (int r = 0; r < 4; ++r){
        int row = wm*32 + mt*16 + lq*4 + r;
        ct[row*132 + wn*64 + nt*16 + lr] = acc[mt][nt][r] + biasf[c0 + row];
      }
  __syncthreads();
  if (*flag){
    float* of = (float*)outv;
#pragma unroll
    for (int i = 0; i < 8; ++i){ int ch = i*256 + t; int r = ch>>5, c4 = (ch&31)*4;
      *(float4*)&of[((size_t)(b*512 + c0 + r))*4096 + n0 + c4] = *(float4*)&ct[r*132 + c4]; }
  } else {
    unsigned short* ob = (unsigned short*)outv;
#pragma unroll
    for (int i = 0; i < 4; ++i){ int ch = i*256 + t; int r = ch>>4, c8 = (ch&15)*8;
      unsigned short tmp[8] __attribute__((aligned(16)));
#pragma unroll
      for (int j = 0; j < 8; ++j) tmp[j] = f2bf(ct[r*132 + c8 + j]);
      *(short8_t*)&ob[((size_t)(b*512 + c0 + r))*4096 + n0 + c8] = *(short8_t*)tmp; }
  }
}

extern "C" void kernel_launch(void* const* d_in, const int* in_sizes, int n_in,
                              void* d_out, int out_size, void* d_ws, size_t ws_size,
                              hipStream_t stream){
  (void)in_sizes; (void)n_in; (void)out_size; (void)ws_size;
  char* ws = (char*)d_ws;
  int* flag              = (int*)ws;
  unsigned short* xT     = (unsigned short*)(ws + OFF_XT);
  unsigned short* Pg     = (unsigned short*)(ws + OFF_KVX);              // [8][4096][128] bf16 = 8 MB
  unsigned short* Mg     = (unsigned short*)(ws + OFF_KVX + 8388608ull); // [8][512][128] bf16
  unsigned short* wkvx   = (unsigned short*)(ws + OFF_WKVX);
  unsigned short* wqx    = (unsigned short*)(ws + OFF_WQX);
  unsigned short* wkvl   = (unsigned short*)(ws + OFF_WKVL);
  unsigned short* wproj  = (unsigned short*)(ws + OFF_WPROJ);
  float* latf  = (float*)(ws + OFF_LATF);
  float* biasf = (float*)(ws + OFF_BIAS);
  float* qlh   = (float*)(ws + OFF_QLH);
  float* gnum  = (float*)(ws + OFF_GNUM);
  float* gden  = (float*)(ws + OFF_GDEN);
  float* kvl   = (float*)(ws + OFF_KVL);
  float* khat  = (float*)(ws + OFF_KHAT);
  float* gvl   = (float*)(ws + OFF_GVL);

  k_sniff<<<1, 256, 0, stream>>>((const unsigned short*)d_in[0], flag);

  // weights (contiguous dst), latents, bias, gnum/gden zero in one launch
  k_prep<<<1030, 256, 0, stream>>>(d_in[3], d_in[4], d_in[5], d_in[6], d_in[2],
                                   d_in[1], d_in[7], wkvx, latf, biasf, gnum, flag);

  k_xt<<<dim3(64, 8, 8), 256, 0, stream>>>(d_in[0], xT, flag);

  k_ql<<<8, 256, 8192 + 17408 + 4096 + 64, stream>>>((unsigned short*)(ws + OFF_WQLAT), latf, qlh);

  k_kvattn1<<<dim3(32, 8, 8), 256, 68608, stream>>>(wkvx, xT, qlh, gnum, gden);
  k_kvl<<<dim3(64, 8), 256, 32768 + 16*136*2, stream>>>(wkvl, gnum, gden, kvl);
  k_klnorm<<<dim3(16, 8, 8), 64, 0, stream>>>(kvl, khat, gvl);
  k_mmat<<<dim3(4, 8, 8), 256, 0, stream>>>(wproj, gvl, Mg);
  k_attn2p2<<<dim3(32, 4, 8), 256, 71168, stream>>>(wqx, xT, khat, Pg);
  k_out<<<dim3(32, 8, 8), 256, 52224, stream>>>(Mg, Pg, biasf, d_out, flag);
}

// Round 9
// 273.829 us; speedup vs baseline: 1.1508x; 1.0481x over previous
//
#include <hip/hip_runtime.h>

// LatentMixer on MI355X. bf16-MFMA pipeline with runtime input-dtype sniffing.
// B=8, C=512, HW=4096, L=16, heads=8, d=64, scale=0.125, eps=1e-12.
// R2: out = (w_proj@blockdiag(V)) @ P + bias.  R3: attn1 fused into kv-GEMM epilogue.
// R4: glld width=16 staging.  R5: XOR-swizzled glld layout.  R7: native __bf16 cast.
// R8: dbuf prefetch gemm.  R9: setprio(1).  R10: attn2p2 on dbuf (281.7us best).
// R12: gnum/gden zeroing folded into k_prep.
// R13: GEMM kernels -> 512 threads / 8 waves (same grid, tile, LDS): waves/CU 8->16
//      to cover the per-step latency remainder; in-register column norms (ssq dropped).

typedef __bf16 bf16x8 __attribute__((ext_vector_type(8)));
typedef float floatx4 __attribute__((ext_vector_type(4)));
typedef short short8_t __attribute__((ext_vector_type(8)));
typedef short short4_t __attribute__((ext_vector_type(4)));

#define DEV __device__ __forceinline__

DEV float bf2f(unsigned short u){ union{unsigned int i; float f;} v; v.i = ((unsigned int)u)<<16; return v.f; }
DEV unsigned short f2bf(float f){
  __bf16 h = (__bf16)f;                  // RTNE; compiler packs pairs into v_cvt_pk_bf16_f32
  unsigned short u; __builtin_memcpy(&u, &h, 2); return u;
}

// async global->LDS, 16 B per lane; LDS dest = base + lane*16 (wave-uniform base!)
DEV void glds16(const void* g, void* l){
  __builtin_amdgcn_global_load_lds((const __attribute__((address_space(1))) void*)g,
                                   (__attribute__((address_space(3))) void*)l, 16, 0, 0);
}

// ---------------- workspace layout (bytes) ----------------
#define OFF_XT     256ull                          // xT bf16 [8][4096][512]
#define OFF_KVX    (OFF_XT + 33554432ull)          // region reused: Pg bf16 [8][4096][128] + Mg
#define OFF_WKVX   (OFF_KVX + 67108864ull)         // w_kv_x bf16   (weights contiguous from here)
#define OFF_WQX    (OFF_WKVX + 1048576ull)         // w_q_x bf16
#define OFF_WKVL   (OFF_WQX + 524288ull)           // w_kv_lat bf16
#define OFF_WPROJ  (OFF_WKVL + 1048576ull)         // w_proj bf16
#define OFF_WQLAT  (OFF_WPROJ + 524288ull)         // w_q_lat bf16
#define OFF_LATF   (OFF_WQLAT + 524288ull)         // latents f32 [512][16]
#define OFF_BIAS   (OFF_LATF + 32768ull)           // bias f32 [512]
#define OFF_QLH    (OFF_BIAS + 4096ull)            // ql-hat f32 [h][l][64] (0.125 folded)
#define OFF_GNUM   (OFF_QLH + 32768ull)            // attn1 numerator f32 [b][h][l][64]
#define OFF_GDEN   (OFF_GNUM + 524288ull)          // attn1 denominator f32 [b][h][l] (contig after gnum)
#define OFF_KVL    (OFF_GDEN + 4096ull)            // kvl f32 [b][1024][16]
#define OFF_KHAT   (OFF_KVL + 524288ull)           // k-hat f32 [b][h][l][64] (0.125 folded)
#define OFF_GVL    (OFF_KHAT + 524288ull)          // vl f32 [b][h][l][64]

// ---------------- dtype sniff ----------------
__global__ void k_sniff(const unsigned short* __restrict__ x, int* flag){
  int t = threadIdx.x;
  int m = 0;
  for (int i = t; i < 4096; i += 256){ int e = (x[i]>>7)&0xFF; m = (e>m)?e:m; }
  __shared__ int red[256];
  red[t] = m; __syncthreads();
  for (int s = 128; s > 0; s >>= 1){ if (t < s) red[t] = (red[t+s]>red[t])?red[t+s]:red[t]; __syncthreads(); }
  if (t == 0) flag[0] = (red[0] > 150) ? 1 : 0;   // 1 => fp32 inputs, 0 => bf16 inputs
}

// ---------------- fused prep: 5 weight converts + latents + bias + gnum/gden zero ----------------
__global__ __launch_bounds__(256) void k_prep(const void* s0, const void* s1, const void* s2,
                                              const void* s3, const void* s4,
                                              const void* slat, const void* sbias,
                                              unsigned short* __restrict__ wdst,
                                              float* __restrict__ latf, float* __restrict__ biasf,
                                              float* __restrict__ zro,
                                              const int* __restrict__ flag){
  int b = blockIdx.x, t = threadIdx.x;
  int isf = *flag;
  if (b < 896){
    int e = b*2048 + t*8;
    const void* src; int off;
    if (e < 524288)      { src = s0; off = e; }
    else if (e < 786432) { src = s1; off = e - 524288; }
    else if (e < 1310720){ src = s2; off = e - 786432; }
    else if (e < 1572864){ src = s3; off = e - 1310720; }
    else                 { src = s4; off = e - 1572864; }
    if (isf){
      const float* s = (const float*)src + off;
      float4 v0 = *(const float4*)(s);
      float4 v1 = *(const float4*)(s+4);
      unsigned short tmp[8] __attribute__((aligned(16)));
      tmp[0]=f2bf(v0.x); tmp[1]=f2bf(v0.y); tmp[2]=f2bf(v0.z); tmp[3]=f2bf(v0.w);
      tmp[4]=f2bf(v1.x); tmp[5]=f2bf(v1.y); tmp[6]=f2bf(v1.z); tmp[7]=f2bf(v1.w);
      *(short8_t*)&wdst[e] = *(short8_t*)tmp;
    } else {
      *(short8_t*)&wdst[e] = *(const short8_t*)((const unsigned short*)src + off);
    }
  } else if (b < 900){
    int i = (b-896)*2048 + t*8;
#pragma unroll
    for (int j = 0; j < 8; ++j)
      latf[i+j] = isf ? ((const float*)slat)[i+j] : bf2f(((const unsigned short*)slat)[i+j]);
  } else if (b == 900){
    if (t < 512) biasf[t] = isf ? ((const float*)sbias)[t] : bf2f(((const unsigned short*)sbias)[t]);
    if (t + 256 < 512) biasf[t+256] = isf ? ((const float*)sbias)[t+256] : bf2f(((const unsigned short*)sbias)[t+256]);
  } else {
    // zero gnum+gden: 528384 B = 33024 float4 = 129 blocks x 256 thr exactly
    int i = (b-901)*256 + t;
    float4 z; z.x=0.f; z.y=0.f; z.z=0.f; z.w=0.f;
    ((float4*)zro)[i] = z;
  }
}

// ---------------- transpose x[b][c][n] -> xT[b][n][c] (bf16) ----------------
__global__ __launch_bounds__(256) void k_xt(const void* __restrict__ xraw, unsigned short* __restrict__ xT,
                                            const int* __restrict__ flag){
  int nb = blockIdx.x, cb = blockIdx.y, b = blockIdx.z;
  int n0 = nb*64, c0 = cb*64;
  __shared__ unsigned short tile[64][72];   // XOR-swizzled columns: col = n ^ (((row>>3)&7)<<3)
  int t = threadIdx.x;
  if (*flag){
    const float* xp = (const float*)xraw;
#pragma unroll
    for (int i = 0; i < 4; ++i){
      int ch = i*256 + t; int c = ch>>4, n4 = (ch&15)*4;
      float4 v = *(const float4*)&xp[((size_t)(b*512 + c0 + c))*4096 + n0 + n4];
      int cc = n4 ^ (((c>>3)&7)<<3);
      tile[c][cc+0]=f2bf(v.x); tile[c][cc+1]=f2bf(v.y); tile[c][cc+2]=f2bf(v.z); tile[c][cc+3]=f2bf(v.w);
    }
  } else {
    const unsigned short* xp = (const unsigned short*)xraw;
#pragma unroll
    for (int i = 0; i < 2; ++i){
      int ch = i*256 + t; int c = ch>>3, n8 = (ch&7)*8;
      *(short8_t*)&tile[c][n8 ^ (((c>>3)&7)<<3)] =
        *(const short8_t*)&xp[((size_t)(b*512 + c0 + c))*4096 + n0 + n8];
    }
  }
  __syncthreads();
#pragma unroll
  for (int i = 0; i < 2; ++i){
    int ch = i*256 + t; int n = ch>>3, c8 = (ch&7)*8;
    unsigned short tmp[8] __attribute__((aligned(16)));
#pragma unroll
    for (int j = 0; j < 8; ++j){
      int c = c8 + j;
      tmp[j] = tile[c][n ^ (((c>>3)&7)<<3)];
    }
    *(short8_t*)&xT[((size_t)(b*4096 + n0 + n))*512 + c0 + c8] = *(short8_t*)tmp;
  }
}

// ---------------- ql = w_q_lat @ latents + normalize -> qlhat [h][l][64], 0.125 folded ----------------
__global__ __launch_bounds__(256) void k_ql(const unsigned short* __restrict__ wqlat,
                                            const float* __restrict__ latf, float* __restrict__ qlh){
  int h = blockIdx.x, o0 = h*64;
  extern __shared__ char smr[];
  float* latb = (float*)smr;                          // [128][16] = 8192
  unsigned short* wt = (unsigned short*)(smr + 8192); // [64][136] = 17408
  float* qbuf = (float*)(smr + 8192 + 17408);         // [64][16] = 4096
  float* rinv = (float*)(smr + 8192 + 17408 + 4096);  // [16]
  int t = threadIdx.x;
  int o = t>>2, l4 = (t&3)*4;
  float acc[4] = {0.f,0.f,0.f,0.f};
  for (int kk = 0; kk < 512; kk += 128){
    __syncthreads();
#pragma unroll
    for (int j = 0; j < 8; ++j){ int i = j*256 + t; latb[i] = latf[kk*16 + i]; }
#pragma unroll
    for (int j = 0; j < 4; ++j){ int ch = j*256 + t; int r = ch>>4, kc = (ch&15)*8;
      *(short8_t*)&wt[r*136 + kc] = *(const short8_t*)&wqlat[(size_t)(o0+r)*512 + kk + kc]; }
    __syncthreads();
    for (int k = 0; k < 128; ++k){
      float w = bf2f(wt[o*136 + k]);
      const float* lr = &latb[k*16 + l4];
#pragma unroll
      for (int j = 0; j < 4; ++j) acc[j] += w*lr[j];
    }
  }
#pragma unroll
  for (int j = 0; j < 4; ++j) qbuf[o*16 + l4 + j] = acc[j];
  __syncthreads();
  if (t < 16){
    float ss = 0.f;
    for (int oo = 0; oo < 64; ++oo){ float v = qbuf[oo*16 + t]; ss += v*v; }
    rinv[t] = 0.125f / fmaxf(sqrtf(ss), 1e-12f);
  }
  __syncthreads();
#pragma unroll
  for (int j = 0; j < 4; ++j) qlh[(h*16 + l4 + j)*64 + o] = acc[j]*rinv[l4 + j];
}

// ---------------- staging helper, 8 waves: waves 0-3 stage A, 4-7 stage B ----------------
DEV void stage_ab8(const unsigned short* __restrict__ Ap0, const unsigned short* __restrict__ Ap1,
                   const unsigned short* __restrict__ Bp, int kk,
                   unsigned short* At, unsigned short* Bt, int wave, int rsub, int koff){
  if (wave < 4){
#pragma unroll
    for (int c2 = 0; c2 < 4; ++c2){
      int chunk = wave*4 + c2;           // 0..15, wave-uniform
      int row = chunk*8 + rsub;
      const unsigned short* gp = (chunk < 8) ? (Ap0 + (size_t)row*512 + kk + koff)
                                             : (Ap1 + (size_t)(row-64)*512 + kk + koff);
      glds16(gp, At + chunk*512);
    }
  } else {
#pragma unroll
    for (int c2 = 0; c2 < 4; ++c2){
      int chunk = (wave-4)*4 + c2;
      int row = chunk*8 + rsub;
      glds16(Bp + (size_t)row*512 + kk + koff, Bt + chunk*512);
    }
  }
}

// ---------------- 128x128 GEMM, dbuf prefetch, 8 waves (512 thr) ----------------
// wm = wave&1 (m half, 64 rows), wn = wave>>1 (n quarter, 32 cols). acc[4][2].
DEV void gemm128_db8(const unsigned short* __restrict__ Ap0, const unsigned short* __restrict__ Ap1,
                     const unsigned short* __restrict__ Bp,
                     char* smr, floatx4 (&acc)[4][2]){
  unsigned short* At0 = (unsigned short*)smr;
  unsigned short* Bt0 = (unsigned short*)(smr + 16384);
  unsigned short* At1 = (unsigned short*)(smr + 32768);
  unsigned short* Bt1 = (unsigned short*)(smr + 49152);
  int t = threadIdx.x, lane = t&63, wave = t>>6;
  int wm = wave&1, wn = wave>>1, lr = lane&15, lq = lane>>4;
  int rsub = lane>>3;                 // 0..7: row within 8-row chunk
  int koff = ((lane&7) ^ rsub)*8;     // swizzled global k8 slot (shorts)
  int sw = lr&7;                      // read-side XOR factor
  stage_ab8(Ap0, Ap1, Bp, 0, At0, Bt0, wave, rsub, koff);
  __syncthreads();                    // tile 0 resident
  for (int kk = 0; kk < 512; kk += 64){
    int cur = (kk>>6)&1;
    unsigned short* Ac = cur ? At1 : At0;
    unsigned short* Bc = cur ? Bt1 : Bt0;
    if (kk < 448){                    // issue next tile's loads FIRST (overlap with compute)
      stage_ab8(Ap0, Ap1, Bp, kk+64, cur ? At0 : At1, cur ? Bt0 : Bt1, wave, rsub, koff);
    }
    __builtin_amdgcn_s_setprio(1);
#pragma unroll
    for (int ks = 0; ks < 2; ++ks){
      int vo = ((ks*4 + lq) ^ sw)*8;
      bf16x8 a[4], b[2];
#pragma unroll
      for (int mt = 0; mt < 4; ++mt) a[mt] = *(const bf16x8*)&Ac[(wm*64 + mt*16 + lr)*64 + vo];
#pragma unroll
      for (int nt = 0; nt < 2; ++nt) b[nt] = *(const bf16x8*)&Bc[(wn*32 + nt*16 + lr)*64 + vo];
#pragma unroll
      for (int mt = 0; mt < 4; ++mt)
#pragma unroll
        for (int nt = 0; nt < 2; ++nt)
          acc[mt][nt] = __builtin_amdgcn_mfma_f32_16x16x32_bf16(a[mt], b[nt], acc[mt][nt], 0, 0, 0);
    }
    __builtin_amdgcn_s_setprio(0);
    __syncthreads();
  }
}

// ---------------- fused kv-GEMM + attn1, 8 waves: M = [k_h(64); v_h(64)], N=128 ----------------
// LDS: staging dbuf 0..65536. Epilogue aliases staging: kt [128][72] @0 (18432),
// vt [64][136] @18432 (->35840), pt [16][136] @35840 (->40192).
// Above staging: qls [16][72] @65536 (->67840), wred [8][16] @67840 (->68352).
__global__ __launch_bounds__(512) void k_kvattn1(const unsigned short* __restrict__ wkvx,
                                                 const unsigned short* __restrict__ xT,
                                                 const float* __restrict__ qlh2,
                                                 float* __restrict__ gnum, float* __restrict__ gden){
  int nb = blockIdx.x, h = blockIdx.y, b = blockIdx.z;
  int n0 = nb*128;
  extern __shared__ char smr[];
  unsigned short* kt  = (unsigned short*)smr;            // [128 n][72] k-hat, d contiguous
  unsigned short* vt  = (unsigned short*)(smr + 18432);  // [64 d][136]
  unsigned short* pt  = (unsigned short*)(smr + 35840);  // [16 l][136] p bf16
  unsigned short* qls = (unsigned short*)(smr + 65536);  // [16 l][72] 0.125*q-hat
  float* wred = (float*)(smr + 67840);                   // [8][16]
  int t = threadIdx.x, lane = t&63, wave = t>>6;
  int wm = wave&1, wn = wave>>1, lr = lane&15, lq = lane>>4;
  // stage 0.125*q-hat [16][72] (outside staging region; before GEMM to overlap)
  for (int i = t; i < 1024; i += 512) qls[(i>>6)*72 + (i&63)] = f2bf(qlh2[(size_t)h*1024 + i]);
  floatx4 acc[4][2];
  floatx4 zero = {0.f,0.f,0.f,0.f};
#pragma unroll
  for (int i = 0; i < 4; ++i) for (int j = 0; j < 2; ++j) acc[i][j] = zero;
  gemm128_db8(wkvx + (size_t)(h*64)*512, wkvx + (size_t)(512 + h*64)*512,
              xT + ((size_t)(b*4096 + n0))*512, smr, acc);
  if (wm == 0){
    // k half: in-register column norms (wave holds all 64 k-rows of its cols) + kt write
#pragma unroll
    for (int nt = 0; nt < 2; ++nt){
      float s = 0.f;
#pragma unroll
      for (int mt = 0; mt < 4; ++mt)
#pragma unroll
        for (int r = 0; r < 4; ++r) s += acc[mt][nt][r]*acc[mt][nt][r];
      s += __shfl_xor(s, 16); s += __shfl_xor(s, 32);
      float rinv = 1.f / fmaxf(sqrtf(s), 1e-12f);
      int col = wn*32 + nt*16 + lr;
#pragma unroll
      for (int mt = 0; mt < 4; ++mt){
        unsigned short tmp[4] __attribute__((aligned(8)));
#pragma unroll
        for (int r = 0; r < 4; ++r) tmp[r] = f2bf(acc[mt][nt][r]*rinv);
        *(short4_t*)&kt[col*72 + mt*16 + lq*4] = *(short4_t*)tmp;
      }
    }
  } else {
    // v half -> vt [d][n]; d = mt*16 + lq*4 + r
#pragma unroll
    for (int mt = 0; mt < 4; ++mt)
#pragma unroll
      for (int nt = 0; nt < 2; ++nt){
        int col = wn*32 + nt*16 + lr;
#pragma unroll
        for (int r = 0; r < 4; ++r) vt[(mt*16 + lq*4 + r)*136 + col] = f2bf(acc[mt][nt][r]);
      }
  }
  __syncthreads();
  // S^T[n][l] via MFMA: A = kt rows n (one 16-row tile per wave), B = qls rows l, K=64
  floatx4 sl = zero;
#pragma unroll
  for (int ks = 0; ks < 2; ++ks){
    bf16x8 bb = *(const bf16x8*)&qls[lr*72 + ks*32 + lq*8];
    bf16x8 aa = *(const bf16x8*)&kt[(wave*16 + lr)*72 + ks*32 + lq*8];
    sl = __builtin_amdgcn_mfma_f32_16x16x32_bf16(aa, bb, sl, 0, 0, 0);
  }
  // p = exp(s) (|s| <= 0.125); den partials; p to LDS [l][n]
  float dp = 0.f;
  float pv[4];
#pragma unroll
  for (int r = 0; r < 4; ++r){ float p = __expf(sl[r]); pv[r] = p; dp += p; }
  dp += __shfl_xor(dp, 16); dp += __shfl_xor(dp, 32);
  if (lq == 0) wred[wave*16 + lr] = dp;
  {
    unsigned short tmp[4] __attribute__((aligned(8)));
#pragma unroll
    for (int r = 0; r < 4; ++r) tmp[r] = f2bf(pv[r]);
    *(short4_t*)&pt[lr*136 + wave*16 + lq*4] = *(short4_t*)tmp;
  }
  __syncthreads();
  int bh = b*8 + h;
  if (t < 16){
    float s = 0.f;
#pragma unroll
    for (int w = 0; w < 8; ++w) s += wred[w*16 + t];
    atomicAdd(&gden[bh*16 + t], s);
  }
  // num^T[d][l] via MFMA: waves 0-3, A = vt rows d (wave*16 tile), B = pt rows l, K=128
  if (wave < 4){
    floatx4 nacc = zero;
#pragma unroll
    for (int ks = 0; ks < 4; ++ks){
      bf16x8 aa = *(const bf16x8*)&vt[(wave*16 + lr)*136 + ks*32 + lq*8];
      bf16x8 bb = *(const bf16x8*)&pt[lr*136 + ks*32 + lq*8];
      nacc = __builtin_amdgcn_mfma_f32_16x16x32_bf16(aa, bb, nacc, 0, 0, 0);
    }
    float* gp = &gnum[((size_t)bh*16 + lr)*64 + wave*16 + lq*4];
#pragma unroll
    for (int r = 0; r < 4; ++r) atomicAdd(&gp[r], nacc[r]);
  }
}

// ---------------- kvl = w_kv_lat @ (num/den), f32 [b][o][l] ----------------
__global__ __launch_bounds__(256) void k_kvl(const unsigned short* __restrict__ wkvl,
                                             const float* __restrict__ gnum, const float* __restrict__ gden,
                                             float* __restrict__ kvl){
  int ob = blockIdx.x, b = blockIdx.y;
  extern __shared__ char smr[];
  float* latb = (float*)smr;                         // [512][16]
  unsigned short* wt = (unsigned short*)(smr + 32768); // [16][136]
  int t = threadIdx.x;
  for (int i = t; i < 8192; i += 256){
    int c = i>>4, l = i&15;
    int h = c>>6, d = c&63;
    int bh = b*8 + h;
    latb[i] = gnum[((size_t)(bh*16 + l))*64 + d] / gden[bh*16 + l];
  }
  int o = t>>4, l = t&15;
  int o0 = ob*16;
  float acc = 0.f;
  for (int kk = 0; kk < 512; kk += 128){
    __syncthreads();
    { int r = t>>4, kc = (t&15)*8;
      *(short8_t*)&wt[r*136 + kc] = *(const short8_t*)&wkvl[(size_t)(o0+r)*512 + kk + kc]; }
    __syncthreads();
    for (int k = 0; k < 128; ++k) acc += bf2f(wt[o*136 + k]) * latb[(kk+k)*16 + l];
  }
  kvl[((size_t)(b*1024 + o0 + o))*16 + l] = acc;
}

// normalize kl per (b,h,l); khat gets 0.125 folded; gvl raw
__global__ void k_klnorm(const float* __restrict__ kvl, float* __restrict__ khat, float* __restrict__ gvl){
  int l = blockIdx.x, h = blockIdx.y, b = blockIdx.z, d = threadIdx.x;
  float kl = kvl[((size_t)(b*1024 + h*64 + d))*16 + l];
  float vl = kvl[((size_t)(b*1024 + 512 + h*64 + d))*16 + l];
  float ss = kl*kl;
  for (int off = 32; off; off >>= 1) ss += __shfl_xor(ss, off);
  float inv = 0.125f / fmaxf(sqrtf(ss), 1e-12f);
  size_t o = ((size_t)((b*8+h)*16 + l))*64 + d;
  khat[o] = kl*inv;
  gvl[o] = vl;
}

// ---------------- Mmat: M[b][c][h*16+l] = sum_d wproj[c][h*64+d] * vl[b][h][l][d] ----------------
__global__ __launch_bounds__(256) void k_mmat(const unsigned short* __restrict__ wproj,
                                              const float* __restrict__ gvl,
                                              unsigned short* __restrict__ Mg){
  int cb = blockIdx.x, h = blockIdx.y, b = blockIdx.z;
  __shared__ unsigned short wt[128*68];
  int t = threadIdx.x;
#pragma unroll
  for (int i = 0; i < 4; ++i){ int ch = i*256 + t; int c = ch>>3, d8 = (ch&7)*8;
    *(short8_t*)&wt[c*68 + d8] = *(const short8_t*)&wproj[(size_t)(cb*128 + c)*512 + h*64 + d8]; }
  int l = t&15, cq = t>>4;
  float v[64];
  const float* vp = &gvl[((size_t)(b*8+h)*16 + l)*64];
#pragma unroll
  for (int j = 0; j < 16; ++j){ float4 f = *(const float4*)&vp[j*4];
    v[j*4+0]=f.x; v[j*4+1]=f.y; v[j*4+2]=f.z; v[j*4+3]=f.w; }
  __syncthreads();
#pragma unroll
  for (int c8 = 0; c8 < 8; ++c8){
    int c = cq*8 + c8;
    float dot = 0.f;
#pragma unroll
    for (int d = 0; d < 64; ++d) dot += bf2f(wt[c*68 + d]) * v[d];
    Mg[((size_t)(b*512) + cb*128 + c)*128 + h*16 + l] = f2bf(dot);
  }
}

// ---------------- attn2 probs, 8 waves: 128x128 q-GEMM (2 heads) + softmax -> P bf16 ----------------
// wm = wave&1 = head-in-pair (64 rows), wn = wave>>1 = n-quarter (32 cols).
// LDS: staging dbuf 0..65536. Epilogue aliases staging: qt0 [128][72] @0, qt1 @18432 (->36864).
// Above staging: khs [2][16][72] @65536 (->70144).
__global__ __launch_bounds__(512) void k_attn2p2(const unsigned short* __restrict__ wqx,
                                                 const unsigned short* __restrict__ xT,
                                                 const float* __restrict__ khatg,
                                                 unsigned short* __restrict__ Pg){
  int nb = blockIdx.x, hp = blockIdx.y, b = blockIdx.z;
  int n0 = nb*128;
  extern __shared__ char smr[];
  unsigned short* qt0 = (unsigned short*)smr;            // head hp*2   q-hat [128 n][72]
  unsigned short* qt1 = (unsigned short*)(smr + 18432);  // head hp*2+1
  unsigned short* khs = (unsigned short*)(smr + 65536);  // [2][16][72]
  int t = threadIdx.x, lane = t&63, wave = t>>6;
  int wm = wave&1, wn = wave>>1, lr = lane&15, lq = lane>>4;
  // stage k-hat (0.125 folded) for both heads (outside staging region)
  for (int i = t; i < 2048; i += 512){
    int hh = i>>10, rem = i&1023;
    khs[hh*1152 + (rem>>6)*72 + (rem&63)] = f2bf(khatg[((size_t)(b*8 + hp*2 + hh))*1024 + rem]);
  }
  floatx4 acc[4][2];
  floatx4 zero = {0.f,0.f,0.f,0.f};
#pragma unroll
  for (int i = 0; i < 4; ++i) for (int j = 0; j < 2; ++j) acc[i][j] = zero;
  gemm128_db8(wqx + (size_t)(hp*128)*512, wqx + (size_t)(hp*128 + 64)*512,
              xT + ((size_t)(b*4096 + n0))*512, smr, acc);
  // per-head column norms in-register (wave holds all 64 rows of head wm for its cols)
  unsigned short* qtr = wm ? qt1 : qt0;
#pragma unroll
  for (int nt = 0; nt < 2; ++nt){
    float s = 0.f;
#pragma unroll
    for (int mt = 0; mt < 4; ++mt)
#pragma unroll
      for (int r = 0; r < 4; ++r) s += acc[mt][nt][r]*acc[mt][nt][r];
    s += __shfl_xor(s, 16); s += __shfl_xor(s, 32);
    float rinv = 1.f / fmaxf(sqrtf(s), 1e-12f);
    int col = wn*32 + nt*16 + lr;
#pragma unroll
    for (int mt = 0; mt < 4; ++mt){
      unsigned short tmp[4] __attribute__((aligned(8)));
#pragma unroll
      for (int r = 0; r < 4; ++r) tmp[r] = f2bf(acc[mt][nt][r]*rinv);
      *(short4_t*)&qtr[col*72 + mt*16 + lq*4] = *(short4_t*)tmp;
    }
  }
  __syncthreads();
  // S^T[n][l]: wave = head wm, n-quarter wn (2 m-tiles), K=64
  floatx4 sl[2];
  sl[0] = zero; sl[1] = zero;
  unsigned short* qsrc = wm ? qt1 : qt0;
#pragma unroll
  for (int ks = 0; ks < 2; ++ks){
    bf16x8 bb = *(const bf16x8*)&khs[wm*1152 + lr*72 + ks*32 + lq*8];
#pragma unroll
    for (int i = 0; i < 2; ++i){
      bf16x8 aa = *(const bf16x8*)&qsrc[((wn*2 + i)*16 + lr)*72 + ks*32 + lq*8];
      sl[i] = __builtin_amdgcn_mfma_f32_16x16x32_bf16(aa, bb, sl[i], 0, 0, 0);
    }
  }
  int h = hp*2 + wm;
#pragma unroll
  for (int i = 0; i < 2; ++i){
    float p[4], s[4];
#pragma unroll
    for (int r = 0; r < 4; ++r){ p[r] = __expf(sl[i][r]); s[r] = p[r]; }
#pragma unroll
    for (int r = 0; r < 4; ++r){
      s[r] += __shfl_xor(s[r], 1);
      s[r] += __shfl_xor(s[r], 2);
      s[r] += __shfl_xor(s[r], 4);
      s[r] += __shfl_xor(s[r], 8);
    }
    int nbase = wn*32 + i*16 + lq*4;
#pragma unroll
    for (int r = 0; r < 4; ++r)
      Pg[((size_t)(b*4096 + n0 + nbase + r))*128 + h*16 + lr] = f2bf(p[r]/s[r]);
  }
}

// ---------------- out = M @ P + bias: 64x128 tile, K=128 ----------------
__global__ __launch_bounds__(256) void k_out(const unsigned short* __restrict__ Mg,
                                             const unsigned short* __restrict__ Pg,
                                             const float* __restrict__ biasf,
                                             void* __restrict__ outv, const int* __restrict__ flag){
  int nb = blockIdx.x, cb = blockIdx.y, b = blockIdx.z;
  int n0 = nb*128, c0 = cb*64;
  extern __shared__ char smr[];
  unsigned short* At = (unsigned short*)smr;   // [64][136]
  unsigned short* Bt = At + 64*136;            // [128][136]
  int t = threadIdx.x, lane = t&63, wave = t>>6;
  int wm = wave>>1, wn = wave&1, lr = lane&15, lq = lane>>4;
#pragma unroll
  for (int i = 0; i < 4; ++i){ int ch = i*256 + t; int r = ch>>4, p8 = (ch&15)*8;
    *(short8_t*)&At[r*136 + p8] = *(const short8_t*)&Mg[((size_t)(b*512 + c0 + r))*128 + p8]; }
#pragma unroll
  for (int i = 0; i < 8; ++i){ int ch = i*256 + t; int r = ch>>4, p8 = (ch&15)*8;
    *(short8_t*)&Bt[r*136 + p8] = *(const short8_t*)&Pg[((size_t)(b*4096 + n0 + r))*128 + p8]; }
  __syncthreads();
  floatx4 acc[2][4];
  floatx4 zero = {0.f,0.f,0.f,0.f};
#pragma unroll
  for (int i = 0; i < 2; ++i) for (int j = 0; j < 4; ++j) acc[i][j] = zero;
#pragma unroll
  for (int ks = 0; ks < 4; ++ks){
    bf16x8 a0 = *(const bf16x8*)&At[(wm*32 + lr)*136 + ks*32 + lq*8];
    bf16x8 a1 = *(const bf16x8*)&At[(wm*32 + 16 + lr)*136 + ks*32 + lq*8];
#pragma unroll
    for (int nt = 0; nt < 4; ++nt){
      bf16x8 bb = *(const bf16x8*)&Bt[(wn*64 + nt*16 + lr)*136 + ks*32 + lq*8];
      acc[0][nt] = __builtin_amdgcn_mfma_f32_16x16x32_bf16(a0, bb, acc[0][nt], 0, 0, 0);
      acc[1][nt] = __builtin_amdgcn_mfma_f32_16x16x32_bf16(a1, bb, acc[1][nt], 0, 0, 0);
    }
  }
  __syncthreads();
  float* ct = (float*)smr;  // [64][132] f32
#pragma unroll
  for (int mt = 0; mt < 2; ++mt)
#pragma unroll
    for (int nt = 0; nt < 4; ++nt)
#pragma unroll
      for (int r = 0; r < 4; ++r){
        int row = wm*32 + mt*16 + lq*4 + r;
        ct[row*132 + wn*64 + nt*16 + lr] = acc[mt][nt][r] + biasf[c0 + row];
      }
  __syncthreads();
  if (*flag){
    float* of = (float*)outv;
#pragma unroll
    for (int i = 0; i < 8; ++i){ int ch = i*256 + t; int r = ch>>5, c4 = (ch&31)*4;
      *(float4*)&of[((size_t)(b*512 + c0 + r))*4096 + n0 + c4] = *(float4*)&ct[r*132 + c4]; }
  } else {
    unsigned short* ob = (unsigned short*)outv;
#pragma unroll
    for (int i = 0; i < 4; ++i){ int ch = i*256 + t; int r = ch>>4, c8 = (ch&15)*8;
      unsigned short tmp[8] __attribute__((aligned(16)));
#pragma unroll
      for (int j = 0; j < 8; ++j) tmp[j] = f2bf(ct[r*132 + c8 + j]);
      *(short8_t*)&ob[((size_t)(b*512 + c0 + r))*4096 + n0 + c8] = *(short8_t*)tmp; }
  }
}

extern "C" void kernel_launch(void* const* d_in, const int* in_sizes, int n_in,
                              void* d_out, int out_size, void* d_ws, size_t ws_size,
                              hipStream_t stream){
  (void)in_sizes; (void)n_in; (void)out_size; (void)ws_size;
  char* ws = (char*)d_ws;
  int* flag              = (int*)ws;
  unsigned short* xT     = (unsigned short*)(ws + OFF_XT);
  unsigned short* Pg     = (unsigned short*)(ws + OFF_KVX);              // [8][4096][128] bf16 = 8 MB
  unsigned short* Mg     = (unsigned short*)(ws + OFF_KVX + 8388608ull); // [8][512][128] bf16
  unsigned short* wkvx   = (unsigned short*)(ws + OFF_WKVX);
  unsigned short* wqx    = (unsigned short*)(ws + OFF_WQX);
  unsigned short* wkvl   = (unsigned short*)(ws + OFF_WKVL);
  unsigned short* wproj  = (unsigned short*)(ws + OFF_WPROJ);
  float* latf  = (float*)(ws + OFF_LATF);
  float* biasf = (float*)(ws + OFF_BIAS);
  float* qlh   = (float*)(ws + OFF_QLH);
  float* gnum  = (float*)(ws + OFF_GNUM);
  float* gden  = (float*)(ws + OFF_GDEN);
  float* kvl   = (float*)(ws + OFF_KVL);
  float* khat  = (float*)(ws + OFF_KHAT);
  float* gvl   = (float*)(ws + OFF_GVL);

  k_sniff<<<1, 256, 0, stream>>>((const unsigned short*)d_in[0], flag);

  // weights (contiguous dst), latents, bias, gnum/gden zero in one launch
  k_prep<<<1030, 256, 0, stream>>>(d_in[3], d_in[4], d_in[5], d_in[6], d_in[2],
                                   d_in[1], d_in[7], wkvx, latf, biasf, gnum, flag);

  k_xt<<<dim3(64, 8, 8), 256, 0, stream>>>(d_in[0], xT, flag);

  k_ql<<<8, 256, 8192 + 17408 + 4096 + 64, stream>>>((unsigned short*)(ws + OFF_WQLAT), latf, qlh);

  k_kvattn1<<<dim3(32, 8, 8), 512, 68352, stream>>>(wkvx, xT, qlh, gnum, gden);
  k_kvl<<<dim3(64, 8), 256, 32768 + 16*136*2, stream>>>(wkvl, gnum, gden, kvl);
  k_klnorm<<<dim3(16, 8, 8), 64, 0, stream>>>(kvl, khat, gvl);
  k_mmat<<<dim3(4, 8, 8), 256, 0, stream>>>(wproj, gvl, Mg);
  k_attn2p2<<<dim3(32, 4, 8), 512, 70144, stream>>>(wqx, xT, khat, Pg);
  k_out<<<dim3(32, 8, 8), 256, 52224, stream>>>(Mg, Pg, biasf, d_out, flag);
}